// Round 1
// baseline (9322.212 us; speedup 1.0000x reference)
//
#include <hip/hip_runtime.h>
#include <hip/hip_bf16.h>

// Problem constants (fixed by setup_inputs)
#define E_NUM 8
#define T_TOK 32768
#define CHUNK 4096
#define HDIM  2048
#define IDIM  8192

typedef __bf16 bf16x8 __attribute__((ext_vector_type(8)));
typedef __bf16 bf16x4 __attribute__((ext_vector_type(4)));
typedef float  f32x4  __attribute__((ext_vector_type(4)));

__device__ inline bf16x4 cvt4(float4 v) {
  bf16x4 r;
  r[0] = (__bf16)v.x; r[1] = (__bf16)v.y; r[2] = (__bf16)v.z; r[3] = (__bf16)v.w;
  return r;
}

// ---------------------------------------------------------------------------
// Fused gate+up GEMM for one expert.
//   g = X (4096x2048 f32) . Gw^T (8192x2048 f32)
//   u = X . Uw^T
//   act[m][n] = silu(g)*u  -> bf16 [4096][8192]
// Tile 128x128, BK=32, 256 threads = 4 waves (2x2), each wave 64x64 out.
// f32 -> bf16 conversion happens in the staging path (reg-staged).
// ---------------------------------------------------------------------------
__global__ __launch_bounds__(256) void gateup_kernel(
    const float* __restrict__ X, const float* __restrict__ Gw,
    const float* __restrict__ Uw, __bf16* __restrict__ act)
{
  __shared__ __bf16 lsA[2][128][32];
  __shared__ __bf16 lsG[2][128][32];
  __shared__ __bf16 lsU[2][128][32];

  const int tid  = threadIdx.x;
  const int lane = tid & 63;
  const int wave = tid >> 6;
  const int wr = wave >> 1, wc = wave & 1;
  const int m0 = blockIdx.y * 128;   // token rows within chunk
  const int n0 = blockIdx.x * 128;   // I columns

  // staging coords: 256 threads, each loads 4x float4 per matrix
  const int sr = tid >> 3;  // 0..31 (row group)
  const int sc = tid & 7;   // 0..7  (float4 within 32-elem row)

  f32x4 accg[4][4], accu[4][4];
#pragma unroll
  for (int m = 0; m < 4; ++m)
#pragma unroll
    for (int n = 0; n < 4; ++n)
#pragma unroll
      for (int j = 0; j < 4; ++j) { accg[m][n][j] = 0.f; accu[m][n][j] = 0.f; }

  float4 ra[4], rg[4], ru[4];

  auto load_regs = [&](int kt) {
    const int k0 = kt * 32;
#pragma unroll
    for (int i = 0; i < 4; ++i) {
      const int row = sr + i * 32;
      ra[i] = *reinterpret_cast<const float4*>(X  + (size_t)(m0 + row) * HDIM + k0 + sc * 4);
      rg[i] = *reinterpret_cast<const float4*>(Gw + (size_t)(n0 + row) * HDIM + k0 + sc * 4);
      ru[i] = *reinterpret_cast<const float4*>(Uw + (size_t)(n0 + row) * HDIM + k0 + sc * 4);
    }
  };
  auto write_lds = [&](int b) {
#pragma unroll
    for (int i = 0; i < 4; ++i) {
      const int row = sr + i * 32;
      *reinterpret_cast<bf16x4*>(&lsA[b][row][sc * 4]) = cvt4(ra[i]);
      *reinterpret_cast<bf16x4*>(&lsG[b][row][sc * 4]) = cvt4(rg[i]);
      *reinterpret_cast<bf16x4*>(&lsU[b][row][sc * 4]) = cvt4(ru[i]);
    }
  };

  const int NT = HDIM / 32;  // 64 K-steps
  load_regs(0);
  write_lds(0);
  int cur = 0;

  const int frow = lane & 15;        // fragment row/col within 16
  const int kcol = (lane >> 4) * 8;  // 8 contiguous k per lane

  for (int kt = 0; kt < NT; ++kt) {
    __syncthreads();
    if (kt + 1 < NT) load_regs(kt + 1);

    bf16x8 af[4];
#pragma unroll
    for (int m = 0; m < 4; ++m)
      af[m] = *reinterpret_cast<const bf16x8*>(&lsA[cur][wr * 64 + m * 16 + frow][kcol]);
#pragma unroll
    for (int n = 0; n < 4; ++n) {
      bf16x8 bg = *reinterpret_cast<const bf16x8*>(&lsG[cur][wc * 64 + n * 16 + frow][kcol]);
      bf16x8 bu = *reinterpret_cast<const bf16x8*>(&lsU[cur][wc * 64 + n * 16 + frow][kcol]);
#pragma unroll
      for (int m = 0; m < 4; ++m) {
        accg[m][n] = __builtin_amdgcn_mfma_f32_16x16x32_bf16(af[m], bg, accg[m][n], 0, 0, 0);
        accu[m][n] = __builtin_amdgcn_mfma_f32_16x16x32_bf16(af[m], bu, accu[m][n], 0, 0, 0);
      }
    }

    __syncthreads();
    if (kt + 1 < NT) write_lds(cur ^ 1);
    cur ^= 1;
  }

  // epilogue: silu(g)*u -> bf16 act
  const int orow = m0 + wr * 64 + (lane >> 4) * 4;  // + m*16 + j
  const int ocol = n0 + wc * 64 + (lane & 15);      // + n*16
#pragma unroll
  for (int m = 0; m < 4; ++m)
#pragma unroll
    for (int n = 0; n < 4; ++n)
#pragma unroll
      for (int j = 0; j < 4; ++j) {
        float g = accg[m][n][j];
        float u = accu[m][n][j];
        float s = g / (1.0f + __expf(-g));
        act[(size_t)(orow + m * 16 + j) * IDIM + (ocol + n * 16)] = (__bf16)(s * u);
      }
}

// ---------------------------------------------------------------------------
// Down GEMM for one expert: out = act (4096x8192 bf16) . Dw^T (2048x8192 f32)
// out f32 [4096][2048] (already offset to this expert's rows).
// ---------------------------------------------------------------------------
__global__ __launch_bounds__(256) void down_kernel(
    const __bf16* __restrict__ act, const float* __restrict__ Dw,
    float* __restrict__ out)
{
  __shared__ __bf16 lsA[2][128][32];
  __shared__ __bf16 lsW[2][128][32];

  const int tid  = threadIdx.x;
  const int lane = tid & 63;
  const int wave = tid >> 6;
  const int wr = wave >> 1, wc = wave & 1;
  const int m0 = blockIdx.y * 128;   // token rows
  const int n0 = blockIdx.x * 128;   // H columns

  // A staging (bf16 source): 128x32 bf16 = 256 threads x 2 x 16B
  const int ar = tid >> 2;  // 0..63
  const int ac = tid & 3;   // 0..3 (16B = 8 bf16)
  // W staging (f32 source): like gateup
  const int sr = tid >> 3;  // 0..31
  const int sc = tid & 7;   // 0..7

  f32x4 acc[4][4];
#pragma unroll
  for (int m = 0; m < 4; ++m)
#pragma unroll
    for (int n = 0; n < 4; ++n)
#pragma unroll
      for (int j = 0; j < 4; ++j) acc[m][n][j] = 0.f;

  uint4  va[2];
  float4 rw[4];

  auto load_regs = [&](int kt) {
    const int k0 = kt * 32;
#pragma unroll
    for (int i = 0; i < 2; ++i)
      va[i] = *reinterpret_cast<const uint4*>(act + (size_t)(m0 + ar + i * 64) * IDIM + k0 + ac * 8);
#pragma unroll
    for (int i = 0; i < 4; ++i)
      rw[i] = *reinterpret_cast<const float4*>(Dw + (size_t)(n0 + sr + i * 32) * IDIM + k0 + sc * 4);
  };
  auto write_lds = [&](int b) {
#pragma unroll
    for (int i = 0; i < 2; ++i)
      *reinterpret_cast<uint4*>(&lsA[b][ar + i * 64][ac * 8]) = va[i];
#pragma unroll
    for (int i = 0; i < 4; ++i)
      *reinterpret_cast<bf16x4*>(&lsW[b][sr + i * 32][sc * 4]) = cvt4(rw[i]);
  };

  const int NT = IDIM / 32;  // 256 K-steps
  load_regs(0);
  write_lds(0);
  int cur = 0;

  const int frow = lane & 15;
  const int kcol = (lane >> 4) * 8;

  for (int kt = 0; kt < NT; ++kt) {
    __syncthreads();
    if (kt + 1 < NT) load_regs(kt + 1);

    bf16x8 af[4];
#pragma unroll
    for (int m = 0; m < 4; ++m)
      af[m] = *reinterpret_cast<const bf16x8*>(&lsA[cur][wr * 64 + m * 16 + frow][kcol]);
#pragma unroll
    for (int n = 0; n < 4; ++n) {
      bf16x8 bw = *reinterpret_cast<const bf16x8*>(&lsW[cur][wc * 64 + n * 16 + frow][kcol]);
#pragma unroll
      for (int m = 0; m < 4; ++m)
        acc[m][n] = __builtin_amdgcn_mfma_f32_16x16x32_bf16(af[m], bw, acc[m][n], 0, 0, 0);
    }

    __syncthreads();
    if (kt + 1 < NT) write_lds(cur ^ 1);
    cur ^= 1;
  }

  const int orow = m0 + wr * 64 + (lane >> 4) * 4;
  const int ocol = n0 + wc * 64 + (lane & 15);
#pragma unroll
  for (int m = 0; m < 4; ++m)
#pragma unroll
    for (int n = 0; n < 4; ++n)
#pragma unroll
      for (int j = 0; j < 4; ++j)
        out[(size_t)(orow + m * 16 + j) * HDIM + (ocol + n * 16)] = acc[m][n][j];
}

// ---------------------------------------------------------------------------
extern "C" void kernel_launch(void* const* d_in, const int* in_sizes, int n_in,
                              void* d_out, int out_size, void* d_ws, size_t ws_size,
                              hipStream_t stream)
{
  const float* hidden = (const float*)d_in[0];
  const float* gate_w = (const float*)d_in[1];
  const float* up_w   = (const float*)d_in[2];
  const float* down_w = (const float*)d_in[3];
  float* out = (float*)d_out;
  __bf16* act = (__bf16*)d_ws;  // CHUNK*IDIM bf16 = 64 MiB, reused per expert

  for (int e = 0; e < E_NUM; ++e) {
    const float* Xe = hidden + (size_t)e * CHUNK * HDIM;
    const float* Ge = gate_w + (size_t)e * IDIM * HDIM;
    const float* Ue = up_w   + (size_t)e * IDIM * HDIM;
    const float* De = down_w + (size_t)e * HDIM * IDIM;
    float* Oe = out + (size_t)e * CHUNK * HDIM;

    gateup_kernel<<<dim3(IDIM / 128, CHUNK / 128), 256, 0, stream>>>(Xe, Ge, Ue, act);
    down_kernel<<<dim3(HDIM / 128, CHUNK / 128), 256, 0, stream>>>(act, De, Oe);
  }
}

// Round 3
// 4034.080 us; speedup vs baseline: 2.3109x; 2.3109x over previous
//
#include <hip/hip_runtime.h>
#include <hip/hip_bf16.h>
#include <stdint.h>

// Problem constants (fixed by setup_inputs)
#define E_NUM 8
#define CHUNK 4096
#define HDIM  2048
#define IDIM  8192

typedef __bf16 bf16x8 __attribute__((ext_vector_type(8)));
typedef __bf16 bf16x4 __attribute__((ext_vector_type(4)));
typedef float  f32x4  __attribute__((ext_vector_type(4)));

#define GLDS16(g, l) __builtin_amdgcn_global_load_lds(                         \
    (const __attribute__((address_space(1))) void*)(g),                        \
    (__attribute__((address_space(3))) void*)(l), 16, 0, 0)

#define MFMA_BF16(a, b, c) __builtin_amdgcn_mfma_f32_16x16x32_bf16((a), (b), (c), 0, 0, 0)

// ---------------------------------------------------------------------------
// f32 -> bf16 conversion (memory-bound, vectorized 8 elems/thread)
// ---------------------------------------------------------------------------
__global__ __launch_bounds__(256) void cvt_kernel(
    const float* __restrict__ src, __bf16* __restrict__ dst)
{
  const size_t i = ((size_t)blockIdx.x * 256 + threadIdx.x) * 8;
  float4 a = *reinterpret_cast<const float4*>(src + i);
  float4 b = *reinterpret_cast<const float4*>(src + i + 4);
  bf16x8 r;
  r[0] = (__bf16)a.x; r[1] = (__bf16)a.y; r[2] = (__bf16)a.z; r[3] = (__bf16)a.w;
  r[4] = (__bf16)b.x; r[5] = (__bf16)b.y; r[6] = (__bf16)b.z; r[7] = (__bf16)b.w;
  *reinterpret_cast<bf16x8*>(dst + i) = r;
}

// ---------------------------------------------------------------------------
// Fused gate+up GEMM (bf16 inputs via global_load_lds + 2-bit XOR swizzle).
//   tile 128x128, BK=32, 4 waves (2x2), each wave 64x64 for BOTH g and u.
//   LDS rows are 64 B (32 bf16) -> only byte-bits 4..5 are within-row free:
//   swizzle: phys = logical ^ (((row>>1)&3)<<4)   (involution, bits 4-5 only)
//   -> 16-lane read groups spread over all 8 bank slot-groups (2-way = free).
//   global_load_lds dest stays LINEAR; the global SOURCE is pre-permuted
//   (rule #21: same involution on source and read, linear write).
// ---------------------------------------------------------------------------
__global__ __launch_bounds__(256) void gateup2_kernel(
    const __bf16* __restrict__ X, const __bf16* __restrict__ Gw,
    const __bf16* __restrict__ Uw, __bf16* __restrict__ act)
{
  __shared__ __bf16 lds[2][3][128 * 32];

  const int tid  = threadIdx.x;
  const int lane = tid & 63;
  const int wave = tid >> 6;
  const int wr = wave >> 1, wc = wave & 1;
  const int m0 = blockIdx.x * 128;   // token rows (consecutive blocks sweep M)
  const int n0 = blockIdx.y * 128;   // I columns

  // staging: per-thread pre-swizzled source coords
  int srow[2], scol[2];
#pragma unroll
  for (int h = 0; h < 2; ++h) {
    const int B  = h * 4096 + tid * 16;          // linear LDS byte this thread fills
    const int Bs = B ^ (((B >> 7) & 3) << 4);    // unswizzle: same involution, row bits intact
    srow[h] = Bs >> 6;                           // source row within tile (0..127)
    scol[h] = (Bs & 63) >> 1;                    // source elem within 32 (0,8,16,24)
  }
  const int ldst_off[2] = { wave * 1024, 4096 + wave * 1024 };  // wave-uniform dest

  f32x4 accg[4][4], accu[4][4];
#pragma unroll
  for (int m = 0; m < 4; ++m)
#pragma unroll
    for (int n = 0; n < 4; ++n)
#pragma unroll
      for (int j = 0; j < 4; ++j) { accg[m][n][j] = 0.f; accu[m][n][j] = 0.f; }

  const int frow  = lane & 15;
  // swizzled k-byte offset within the row: kgroup*16 ^ (((row>>1)&3)<<4); stays in [0,64)
  const int rdoff = ((lane >> 4) * 16) ^ (((frow >> 1) & 3) << 4);

  auto stage = [&](int buf, int kt) {
    const int k0 = kt * 32;
#pragma unroll
    for (int h = 0; h < 2; ++h) {
      const __bf16* gA = X  + (size_t)(m0 + srow[h]) * HDIM + k0 + scol[h];
      const __bf16* gG = Gw + (size_t)(n0 + srow[h]) * HDIM + k0 + scol[h];
      const __bf16* gU = Uw + (size_t)(n0 + srow[h]) * HDIM + k0 + scol[h];
      GLDS16(gA, (char*)&lds[buf][0][0] + ldst_off[h]);
      GLDS16(gG, (char*)&lds[buf][1][0] + ldst_off[h]);
      GLDS16(gU, (char*)&lds[buf][2][0] + ldst_off[h]);
    }
  };

  const int NT = HDIM / 32;  // 64
  stage(0, 0);
  int cur = 0;

  for (int kt = 0; kt < NT; ++kt) {
    __syncthreads();                    // compiler drains vmcnt+lgkmcnt here
    if (kt + 1 < NT) stage(cur ^ 1, kt + 1);

    const char* bA = (const char*)&lds[cur][0][0];
    const char* bG = (const char*)&lds[cur][1][0];
    const char* bU = (const char*)&lds[cur][2][0];

    bf16x8 af[4];
#pragma unroll
    for (int m = 0; m < 4; ++m)
      af[m] = *(const bf16x8*)(bA + (wr * 64 + m * 16 + frow) * 64 + rdoff);
#pragma unroll
    for (int n = 0; n < 4; ++n) {
      bf16x8 bg = *(const bf16x8*)(bG + (wc * 64 + n * 16 + frow) * 64 + rdoff);
      bf16x8 bu = *(const bf16x8*)(bU + (wc * 64 + n * 16 + frow) * 64 + rdoff);
#pragma unroll
      for (int m = 0; m < 4; ++m) {
        accg[m][n] = MFMA_BF16(af[m], bg, accg[m][n]);
        accu[m][n] = MFMA_BF16(af[m], bu, accu[m][n]);
      }
    }
    cur ^= 1;
  }

  // epilogue: silu(g)*u -> bf16 act
  const int orow = m0 + wr * 64 + (lane >> 4) * 4;
  const int ocol = n0 + wc * 64 + (lane & 15);
#pragma unroll
  for (int m = 0; m < 4; ++m)
#pragma unroll
    for (int n = 0; n < 4; ++n)
#pragma unroll
      for (int j = 0; j < 4; ++j) {
        float g = accg[m][n][j];
        float u = accu[m][n][j];
        float s = g / (1.0f + __expf(-g));
        act[(size_t)(orow + m * 16 + j) * IDIM + (ocol + n * 16)] = (__bf16)(s * u);
      }
}

// ---------------------------------------------------------------------------
// Down GEMM: out = act (4096x8192 bf16) . Dw^T (2048x8192 bf16) -> f32
// Same structure, 2 staged matrices, NT = 256.
// ---------------------------------------------------------------------------
__global__ __launch_bounds__(256) void down2_kernel(
    const __bf16* __restrict__ act, const __bf16* __restrict__ Dw,
    float* __restrict__ out)
{
  __shared__ __bf16 lds[2][2][128 * 32];

  const int tid  = threadIdx.x;
  const int lane = tid & 63;
  const int wave = tid >> 6;
  const int wr = wave >> 1, wc = wave & 1;
  const int m0 = blockIdx.x * 128;   // token rows
  const int n0 = blockIdx.y * 128;   // H columns

  int srow[2], scol[2];
#pragma unroll
  for (int h = 0; h < 2; ++h) {
    const int B  = h * 4096 + tid * 16;
    const int Bs = B ^ (((B >> 7) & 3) << 4);
    srow[h] = Bs >> 6;
    scol[h] = (Bs & 63) >> 1;
  }
  const int ldst_off[2] = { wave * 1024, 4096 + wave * 1024 };

  f32x4 acc[4][4];
#pragma unroll
  for (int m = 0; m < 4; ++m)
#pragma unroll
    for (int n = 0; n < 4; ++n)
#pragma unroll
      for (int j = 0; j < 4; ++j) acc[m][n][j] = 0.f;

  const int frow  = lane & 15;
  const int rdoff = ((lane >> 4) * 16) ^ (((frow >> 1) & 3) << 4);

  auto stage = [&](int buf, int kt) {
    const int k0 = kt * 32;
#pragma unroll
    for (int h = 0; h < 2; ++h) {
      const __bf16* gA = act + (size_t)(m0 + srow[h]) * IDIM + k0 + scol[h];
      const __bf16* gW = Dw  + (size_t)(n0 + srow[h]) * IDIM + k0 + scol[h];
      GLDS16(gA, (char*)&lds[buf][0][0] + ldst_off[h]);
      GLDS16(gW, (char*)&lds[buf][1][0] + ldst_off[h]);
    }
  };

  const int NT = IDIM / 32;  // 256
  stage(0, 0);
  int cur = 0;

  for (int kt = 0; kt < NT; ++kt) {
    __syncthreads();
    if (kt + 1 < NT) stage(cur ^ 1, kt + 1);

    const char* bA = (const char*)&lds[cur][0][0];
    const char* bW = (const char*)&lds[cur][1][0];

    bf16x8 af[4];
#pragma unroll
    for (int m = 0; m < 4; ++m)
      af[m] = *(const bf16x8*)(bA + (wr * 64 + m * 16 + frow) * 64 + rdoff);
#pragma unroll
    for (int n = 0; n < 4; ++n) {
      bf16x8 bw = *(const bf16x8*)(bW + (wc * 64 + n * 16 + frow) * 64 + rdoff);
#pragma unroll
      for (int m = 0; m < 4; ++m)
        acc[m][n] = MFMA_BF16(af[m], bw, acc[m][n]);
    }
    cur ^= 1;
  }

  const int orow = m0 + wr * 64 + (lane >> 4) * 4;
  const int ocol = n0 + wc * 64 + (lane & 15);
#pragma unroll
  for (int m = 0; m < 4; ++m)
#pragma unroll
    for (int n = 0; n < 4; ++n)
#pragma unroll
      for (int j = 0; j < 4; ++j)
        out[(size_t)(orow + m * 16 + j) * HDIM + (ocol + n * 16)] = acc[m][n][j];
}

// ===========================================================================
// Fallback path (round-1 kernels, reg-staged f32->bf16) if ws is small.
// ===========================================================================
__device__ inline bf16x4 cvt4(float4 v) {
  bf16x4 r;
  r[0] = (__bf16)v.x; r[1] = (__bf16)v.y; r[2] = (__bf16)v.z; r[3] = (__bf16)v.w;
  return r;
}

__global__ __launch_bounds__(256) void gateup_fb_kernel(
    const float* __restrict__ X, const float* __restrict__ Gw,
    const float* __restrict__ Uw, __bf16* __restrict__ act)
{
  __shared__ __bf16 lsA[2][128][32];
  __shared__ __bf16 lsG[2][128][32];
  __shared__ __bf16 lsU[2][128][32];

  const int tid  = threadIdx.x;
  const int lane = tid & 63;
  const int wave = tid >> 6;
  const int wr = wave >> 1, wc = wave & 1;
  const int m0 = blockIdx.y * 128;
  const int n0 = blockIdx.x * 128;
  const int sr = tid >> 3;
  const int sc = tid & 7;

  f32x4 accg[4][4], accu[4][4];
#pragma unroll
  for (int m = 0; m < 4; ++m)
#pragma unroll
    for (int n = 0; n < 4; ++n)
#pragma unroll
      for (int j = 0; j < 4; ++j) { accg[m][n][j] = 0.f; accu[m][n][j] = 0.f; }

  float4 ra[4], rg[4], ru[4];
  auto load_regs = [&](int kt) {
    const int k0 = kt * 32;
#pragma unroll
    for (int i = 0; i < 4; ++i) {
      const int row = sr + i * 32;
      ra[i] = *reinterpret_cast<const float4*>(X  + (size_t)(m0 + row) * HDIM + k0 + sc * 4);
      rg[i] = *reinterpret_cast<const float4*>(Gw + (size_t)(n0 + row) * HDIM + k0 + sc * 4);
      ru[i] = *reinterpret_cast<const float4*>(Uw + (size_t)(n0 + row) * HDIM + k0 + sc * 4);
    }
  };
  auto write_lds = [&](int b) {
#pragma unroll
    for (int i = 0; i < 4; ++i) {
      const int row = sr + i * 32;
      *reinterpret_cast<bf16x4*>(&lsA[b][row][sc * 4]) = cvt4(ra[i]);
      *reinterpret_cast<bf16x4*>(&lsG[b][row][sc * 4]) = cvt4(rg[i]);
      *reinterpret_cast<bf16x4*>(&lsU[b][row][sc * 4]) = cvt4(ru[i]);
    }
  };

  const int NT = HDIM / 32;
  load_regs(0);
  write_lds(0);
  int cur = 0;
  const int frow = lane & 15;
  const int kcol = (lane >> 4) * 8;

  for (int kt = 0; kt < NT; ++kt) {
    __syncthreads();
    if (kt + 1 < NT) load_regs(kt + 1);
    bf16x8 af[4];
#pragma unroll
    for (int m = 0; m < 4; ++m)
      af[m] = *reinterpret_cast<const bf16x8*>(&lsA[cur][wr * 64 + m * 16 + frow][kcol]);
#pragma unroll
    for (int n = 0; n < 4; ++n) {
      bf16x8 bg = *reinterpret_cast<const bf16x8*>(&lsG[cur][wc * 64 + n * 16 + frow][kcol]);
      bf16x8 bu = *reinterpret_cast<const bf16x8*>(&lsU[cur][wc * 64 + n * 16 + frow][kcol]);
#pragma unroll
      for (int m = 0; m < 4; ++m) {
        accg[m][n] = MFMA_BF16(af[m], bg, accg[m][n]);
        accu[m][n] = MFMA_BF16(af[m], bu, accu[m][n]);
      }
    }
    __syncthreads();
    if (kt + 1 < NT) write_lds(cur ^ 1);
    cur ^= 1;
  }

  const int orow = m0 + wr * 64 + (lane >> 4) * 4;
  const int ocol = n0 + wc * 64 + (lane & 15);
#pragma unroll
  for (int m = 0; m < 4; ++m)
#pragma unroll
    for (int n = 0; n < 4; ++n)
#pragma unroll
      for (int j = 0; j < 4; ++j) {
        float g = accg[m][n][j];
        float u = accu[m][n][j];
        float s = g / (1.0f + __expf(-g));
        act[(size_t)(orow + m * 16 + j) * IDIM + (ocol + n * 16)] = (__bf16)(s * u);
      }
}

__global__ __launch_bounds__(256) void down_fb_kernel(
    const __bf16* __restrict__ act, const float* __restrict__ Dw,
    float* __restrict__ out)
{
  __shared__ __bf16 lsA[2][128][32];
  __shared__ __bf16 lsW[2][128][32];

  const int tid  = threadIdx.x;
  const int lane = tid & 63;
  const int wave = tid >> 6;
  const int wr = wave >> 1, wc = wave & 1;
  const int m0 = blockIdx.y * 128;
  const int n0 = blockIdx.x * 128;
  const int ar = tid >> 2;
  const int ac = tid & 3;
  const int sr = tid >> 3;
  const int sc = tid & 7;

  f32x4 acc[4][4];
#pragma unroll
  for (int m = 0; m < 4; ++m)
#pragma unroll
    for (int n = 0; n < 4; ++n)
#pragma unroll
      for (int j = 0; j < 4; ++j) acc[m][n][j] = 0.f;

  uint4  va[2];
  float4 rw[4];
  auto load_regs = [&](int kt) {
    const int k0 = kt * 32;
#pragma unroll
    for (int i = 0; i < 2; ++i)
      va[i] = *reinterpret_cast<const uint4*>(act + (size_t)(m0 + ar + i * 64) * IDIM + k0 + ac * 8);
#pragma unroll
    for (int i = 0; i < 4; ++i)
      rw[i] = *reinterpret_cast<const float4*>(Dw + (size_t)(n0 + sr + i * 32) * IDIM + k0 + sc * 4);
  };
  auto write_lds = [&](int b) {
#pragma unroll
    for (int i = 0; i < 2; ++i)
      *reinterpret_cast<uint4*>(&lsA[b][ar + i * 64][ac * 8]) = va[i];
#pragma unroll
    for (int i = 0; i < 4; ++i)
      *reinterpret_cast<bf16x4*>(&lsW[b][sr + i * 32][sc * 4]) = cvt4(rw[i]);
  };

  const int NT = IDIM / 32;
  load_regs(0);
  write_lds(0);
  int cur = 0;
  const int frow = lane & 15;
  const int kcol = (lane >> 4) * 8;

  for (int kt = 0; kt < NT; ++kt) {
    __syncthreads();
    if (kt + 1 < NT) load_regs(kt + 1);
    bf16x8 af[4];
#pragma unroll
    for (int m = 0; m < 4; ++m)
      af[m] = *reinterpret_cast<const bf16x8*>(&lsA[cur][wr * 64 + m * 16 + frow][kcol]);
#pragma unroll
    for (int n = 0; n < 4; ++n) {
      bf16x8 bw = *reinterpret_cast<const bf16x8*>(&lsW[cur][wc * 64 + n * 16 + frow][kcol]);
#pragma unroll
      for (int m = 0; m < 4; ++m)
        acc[m][n] = MFMA_BF16(af[m], bw, acc[m][n]);
    }
    __syncthreads();
    if (kt + 1 < NT) write_lds(cur ^ 1);
    cur ^= 1;
  }

  const int orow = m0 + wr * 64 + (lane >> 4) * 4;
  const int ocol = n0 + wc * 64 + (lane & 15);
#pragma unroll
  for (int m = 0; m < 4; ++m)
#pragma unroll
    for (int n = 0; n < 4; ++n)
#pragma unroll
      for (int j = 0; j < 4; ++j)
        out[(size_t)(orow + m * 16 + j) * HDIM + (ocol + n * 16)] = acc[m][n][j];
}

// ---------------------------------------------------------------------------
extern "C" void kernel_launch(void* const* d_in, const int* in_sizes, int n_in,
                              void* d_out, int out_size, void* d_ws, size_t ws_size,
                              hipStream_t stream)
{
  const float* hidden = (const float*)d_in[0];
  const float* gate_w = (const float*)d_in[1];
  const float* up_w   = (const float*)d_in[2];
  const float* down_w = (const float*)d_in[3];
  float* out = (float*)d_out;

  // ws layout (bf16):  Xe | Ge | Ue | De | act
  const size_t SZ_X   = (size_t)CHUNK * HDIM;
  const size_t SZ_W   = (size_t)IDIM * HDIM;
  const size_t SZ_ACT = (size_t)CHUNK * IDIM;
  const size_t need = (SZ_X + 3 * SZ_W + SZ_ACT) * sizeof(__bf16);  // ~176 MiB

  if (ws_size >= need) {
    __bf16* xb = (__bf16*)d_ws;
    __bf16* gb = xb + SZ_X;
    __bf16* ub = gb + SZ_W;
    __bf16* db = ub + SZ_W;
    __bf16* act = db + SZ_W;

    for (int e = 0; e < E_NUM; ++e) {
      const float* Xe = hidden + (size_t)e * SZ_X;
      const float* Ge = gate_w + (size_t)e * SZ_W;
      const float* Ue = up_w   + (size_t)e * SZ_W;
      const float* De = down_w + (size_t)e * SZ_W;
      float* Oe = out + (size_t)e * CHUNK * HDIM;

      cvt_kernel<<<SZ_X / 2048, 256, 0, stream>>>(Xe, xb);
      cvt_kernel<<<SZ_W / 2048, 256, 0, stream>>>(Ge, gb);
      cvt_kernel<<<SZ_W / 2048, 256, 0, stream>>>(Ue, ub);
      cvt_kernel<<<SZ_W / 2048, 256, 0, stream>>>(De, db);

      // bx sweeps M (consecutive blocks share the weight panel -> weights ~1 fetch)
      gateup2_kernel<<<dim3(CHUNK / 128, IDIM / 128), 256, 0, stream>>>(xb, gb, ub, act);
      down2_kernel<<<dim3(CHUNK / 128, HDIM / 128), 256, 0, stream>>>(act, db, Oe);
    }
  } else {
    __bf16* act = (__bf16*)d_ws;
    for (int e = 0; e < E_NUM; ++e) {
      const float* Xe = hidden + (size_t)e * SZ_X;
      const float* Ge = gate_w + (size_t)e * SZ_W;
      const float* Ue = up_w   + (size_t)e * SZ_W;
      const float* De = down_w + (size_t)e * SZ_W;
      float* Oe = out + (size_t)e * CHUNK * HDIM;
      gateup_fb_kernel<<<dim3(IDIM / 128, CHUNK / 128), 256, 0, stream>>>(Xe, Ge, Ue, act);
      down_fb_kernel<<<dim3(HDIM / 128, CHUNK / 128), 256, 0, stream>>>(act, De, Oe);
    }
  }
}

// Round 4
// 3727.846 us; speedup vs baseline: 2.5007x; 1.0821x over previous
//
#include <hip/hip_runtime.h>
#include <hip/hip_bf16.h>
#include <stdint.h>

// Problem constants (fixed by setup_inputs)
#define E_NUM 8
#define CHUNK 4096
#define HDIM  2048
#define IDIM  8192

typedef __bf16 bf16x8 __attribute__((ext_vector_type(8)));
typedef __bf16 bf16x4 __attribute__((ext_vector_type(4)));
typedef float  f32x4  __attribute__((ext_vector_type(4)));

#define GLDS16(g, l) __builtin_amdgcn_global_load_lds(                         \
    (const __attribute__((address_space(1))) void*)(g),                        \
    (__attribute__((address_space(3))) void*)(l), 16, 0, 0)
#define MFMA(a, b, c) __builtin_amdgcn_mfma_f32_16x16x32_bf16((a), (b), (c), 0, 0, 0)
#define FENCE() asm volatile("" ::: "memory")
#define BAR()   do { FENCE(); __builtin_amdgcn_s_barrier(); FENCE(); } while (0)
#define WAITV(n) asm volatile("s_waitcnt vmcnt(" #n ")" ::: "memory")

// frag read from a 128-row x 128B LDS region with st_16x32 swizzle
#define RDF(base, rp, ks) \
  (*(const bf16x8*)((base) + (rp) * 128 + ((((ks) * 64) + q16) ^ ((((rp) >> 2) & 1) << 5))))

// ---------------------------------------------------------------------------
// f32 -> bf16 conversion (memory-bound, 8 elems/thread)
// ---------------------------------------------------------------------------
__global__ __launch_bounds__(256) void cvt_kernel(
    const float* __restrict__ src, __bf16* __restrict__ dst)
{
  const size_t i = ((size_t)blockIdx.x * 256 + threadIdx.x) * 8;
  float4 a = *reinterpret_cast<const float4*>(src + i);
  float4 b = *reinterpret_cast<const float4*>(src + i + 4);
  bf16x8 r;
  r[0] = (__bf16)a.x; r[1] = (__bf16)a.y; r[2] = (__bf16)a.z; r[3] = (__bf16)a.w;
  r[4] = (__bf16)b.x; r[5] = (__bf16)b.y; r[6] = (__bf16)b.z; r[7] = (__bf16)b.w;
  *reinterpret_cast<bf16x8*>(dst + i) = r;
}

// ===========================================================================
// 8-phase fused gate+up GEMM.  BM=256 (tokens) x BN=128 (cols of BOTH g,u),
// BK=64. 8 waves as 4M x 2N; per-wave 64x64 per matrix; acc 2x16 f32x4.
// LDS per buffer (64KB): Ah0@0, Ah1@16K, G@32K, U@48K (each 128 rows x 128B).
// A region h holds tile rows {wm*64 + h*32 + 0..31 : wm}, row' = wm*32+(mf&1)*16+f.
// Phases per K-tile: ph0 g*mh0, ph1 u*mh0, ph2 g*mh1, ph3 u*mh1.
// Stage slots: ph0->(t+1,Ah1) ph1->(t+1,U) ph2->(t+2,Ah0) ph3->(t+2,G).
// Boundary s_waitcnt vmcnt(4) (vmcnt(0) at t==NT-2).
// ===========================================================================
__global__ __launch_bounds__(512, 2) void gateup8_kernel(
    const __bf16* __restrict__ X, const __bf16* __restrict__ Gw,
    const __bf16* __restrict__ Uw, __bf16* __restrict__ act)
{
  extern __shared__ char smem[];   // 2 x 64KB
  const int tid  = threadIdx.x;
  const int lane = tid & 63;
  const int wave = tid >> 6;
  const int wm = wave >> 1, wn = wave & 1;
  const int e  = blockIdx.z;
  const int m0 = e * CHUNK + blockIdx.x * 256;   // row into X/act
  const int n0 = e * IDIM  + blockIdx.y * 128;   // row into Gw/Uw

  // staging precompute: linear dest byte P -> pre-swizzled source (row,col)
  int su[2], skk[2];
#pragma unroll
  for (int j = 0; j < 2; ++j) {
    int P = j * 8192 + tid * 16;
    int L = P ^ (((P >> 9) & 1) << 5);
    su[j]  = L >> 7;          // row-in-region 0..127
    skk[j] = (L & 127) >> 1;  // k elem offset (multiple of 8)
  }
  const int ldsw = wave * 1024;  // wave-uniform dest offset within 8KB chunk

  auto stageA = [&](char* bb, int h, int kt2) {
#pragma unroll
    for (int j = 0; j < 2; ++j) {
      int u = su[j];
      int r = (u & 31) + h * 32 + (u >> 5) * 64;
      const __bf16* src = X + (size_t)(m0 + r) * HDIM + kt2 * 64 + skk[j];
      GLDS16(src, bb + h * 16384 + j * 8192 + ldsw);
    }
  };
  auto stageW = [&](char* bb, int w, int kt2) {   // w: 0=G, 1=U
    const __bf16* W = w ? Uw : Gw;
#pragma unroll
    for (int j = 0; j < 2; ++j) {
      const __bf16* src = W + (size_t)(n0 + su[j]) * HDIM + kt2 * 64 + skk[j];
      GLDS16(src, bb + 32768 + w * 16384 + j * 8192 + ldsw);
    }
  };

  f32x4 accg[4][4], accu[4][4];
#pragma unroll
  for (int m = 0; m < 4; ++m)
#pragma unroll
    for (int n = 0; n < 4; ++n)
#pragma unroll
      for (int j = 0; j < 4; ++j) { accg[m][n][j] = 0.f; accu[m][n][j] = 0.f; }

  const int frow = lane & 15;
  const int q16  = (lane >> 4) * 16;
  const int NT   = HDIM / 64;   // 32

  // prologue: tile0 {Ah0,G,Ah1,U}, tile1 {Ah0,G}; then drain to 2 units
  {
    char* s0 = smem;
    char* s1 = smem + 65536;
    stageA(s0, 0, 0); stageW(s0, 0, 0); stageA(s0, 1, 0); stageW(s0, 1, 0);
    stageA(s1, 0, 1); stageW(s1, 0, 1);
  }
  WAITV(4); BAR();

  for (int kt = 0; kt < NT; ++kt) {
    const int b = kt & 1;
    char* sb = smem + b * 65536;
    char* so = smem + (b ^ 1) * 65536;
    bf16x8 aF[2][2], wF[4][2];

    // ---- phase 0: g, mh0 ----
#pragma unroll
    for (int m = 0; m < 2; ++m) { int rp = wm * 32 + m * 16 + frow;
      aF[m][0] = RDF(sb, rp, 0); aF[m][1] = RDF(sb, rp, 1); }
#pragma unroll
    for (int n = 0; n < 4; ++n) { int rp = wn * 64 + n * 16 + frow;
      wF[n][0] = RDF(sb + 32768, rp, 0); wF[n][1] = RDF(sb + 32768, rp, 1); }
    if (kt + 1 < NT) stageA(so, 1, kt + 1);
    BAR();
    __builtin_amdgcn_s_setprio(1);
#pragma unroll
    for (int n = 0; n < 4; ++n)
#pragma unroll
      for (int m = 0; m < 2; ++m) {
        accg[m][n] = MFMA(aF[m][0], wF[n][0], accg[m][n]);
        accg[m][n] = MFMA(aF[m][1], wF[n][1], accg[m][n]);
      }
    __builtin_amdgcn_s_setprio(0);
    BAR();

    // ---- phase 1: u, mh0 (A frags reused) ----
#pragma unroll
    for (int n = 0; n < 4; ++n) { int rp = wn * 64 + n * 16 + frow;
      wF[n][0] = RDF(sb + 49152, rp, 0); wF[n][1] = RDF(sb + 49152, rp, 1); }
    if (kt + 1 < NT) stageW(so, 1, kt + 1);
    BAR();
    __builtin_amdgcn_s_setprio(1);
#pragma unroll
    for (int n = 0; n < 4; ++n)
#pragma unroll
      for (int m = 0; m < 2; ++m) {
        accu[m][n] = MFMA(aF[m][0], wF[n][0], accu[m][n]);
        accu[m][n] = MFMA(aF[m][1], wF[n][1], accu[m][n]);
      }
    __builtin_amdgcn_s_setprio(0);
    BAR();

    // ---- phase 2: g, mh1 ----
#pragma unroll
    for (int m = 0; m < 2; ++m) { int rp = wm * 32 + m * 16 + frow;
      aF[m][0] = RDF(sb + 16384, rp, 0); aF[m][1] = RDF(sb + 16384, rp, 1); }
#pragma unroll
    for (int n = 0; n < 4; ++n) { int rp = wn * 64 + n * 16 + frow;
      wF[n][0] = RDF(sb + 32768, rp, 0); wF[n][1] = RDF(sb + 32768, rp, 1); }
    if (kt + 2 < NT) stageA(sb, 0, kt + 2);
    BAR();
    __builtin_amdgcn_s_setprio(1);
#pragma unroll
    for (int n = 0; n < 4; ++n)
#pragma unroll
      for (int m = 0; m < 2; ++m) {
        accg[2 + m][n] = MFMA(aF[m][0], wF[n][0], accg[2 + m][n]);
        accg[2 + m][n] = MFMA(aF[m][1], wF[n][1], accg[2 + m][n]);
      }
    __builtin_amdgcn_s_setprio(0);
    BAR();

    // ---- phase 3: u, mh1 ----
#pragma unroll
    for (int n = 0; n < 4; ++n) { int rp = wn * 64 + n * 16 + frow;
      wF[n][0] = RDF(sb + 49152, rp, 0); wF[n][1] = RDF(sb + 49152, rp, 1); }
    if (kt + 2 < NT) stageW(sb, 0, kt + 2);
    BAR();
    __builtin_amdgcn_s_setprio(1);
#pragma unroll
    for (int n = 0; n < 4; ++n)
#pragma unroll
      for (int m = 0; m < 2; ++m) {
        accu[2 + m][n] = MFMA(aF[m][0], wF[n][0], accu[2 + m][n]);
        accu[2 + m][n] = MFMA(aF[m][1], wF[n][1], accu[2 + m][n]);
      }
    __builtin_amdgcn_s_setprio(0);
    if (kt < NT - 2) { WAITV(4); } else if (kt == NT - 2) { WAITV(0); }
    BAR();
  }

  // epilogue: silu(g)*u -> bf16 act
  const int orow0 = m0 + wm * 64 + (lane >> 4) * 4;
  const int ocol0 = blockIdx.y * 128 + wn * 64 + frow;
#pragma unroll
  for (int m = 0; m < 4; ++m)
#pragma unroll
    for (int n = 0; n < 4; ++n)
#pragma unroll
      for (int j = 0; j < 4; ++j) {
        float g = accg[m][n][j];
        float u = accu[m][n][j];
        float s = g / (1.0f + __expf(-g));
        act[(size_t)(orow0 + m * 16 + j) * IDIM + (ocol0 + n * 16)] = (__bf16)(s * u);
      }
}

// ===========================================================================
// 8-phase down GEMM (grouped over experts): out = act . Dw^T  (f32 out)
// BM=BN=256, BK=64. 8 waves as 2M x 4N; per-wave 128x64; acc[8][4].
// LDS per buffer: Ah0@0 Ah1@16K Bh0@32K Bh1@48K.
// A region h: rows {wr*128 + h*64 + 0..63}, row' = wr*64+(mf&3)*16+f.
// B region h: rows {wc*64 + h*32 + 0..31}, row' = wc*32+(nf&1)*16+f.
// Phases: ph0 (mh0,nh0) ph1 (mh0,nh1) ph2 (mh1,nh0) ph3 (mh1,nh1).
// Stage slots: ph0->(t+1,Ah1) ph1->(t+1,Bh1) ph2->(t+2,Ah0) ph3->(t+2,Bh0).
// ===========================================================================
__global__ __launch_bounds__(512, 2) void down8_kernel(
    const __bf16* __restrict__ act, const __bf16* __restrict__ Dw,
    float* __restrict__ out)
{
  extern __shared__ char smem[];
  const int tid  = threadIdx.x;
  const int lane = tid & 63;
  const int wave = tid >> 6;
  const int wr = wave >> 2, wc = wave & 3;
  const int e  = blockIdx.z;
  const int m0 = e * CHUNK + blockIdx.x * 256;   // row into act/out
  const int n0 = e * HDIM  + blockIdx.y * 256;   // row into Dw

  int su[2], skk[2];
#pragma unroll
  for (int j = 0; j < 2; ++j) {
    int P = j * 8192 + tid * 16;
    int L = P ^ (((P >> 9) & 1) << 5);
    su[j]  = L >> 7;
    skk[j] = (L & 127) >> 1;
  }
  const int ldsw = wave * 1024;

  auto stageA = [&](char* bb, int h, int kt2) {
#pragma unroll
    for (int j = 0; j < 2; ++j) {
      int u = su[j];
      int r = (u & 63) + h * 64 + (u >> 6) * 128;
      const __bf16* src = act + (size_t)(m0 + r) * IDIM + kt2 * 64 + skk[j];
      GLDS16(src, bb + h * 16384 + j * 8192 + ldsw);
    }
  };
  auto stageB = [&](char* bb, int h, int kt2) {
#pragma unroll
    for (int j = 0; j < 2; ++j) {
      int u = su[j];
      int r = (u & 31) + h * 32 + (u >> 5) * 64;
      const __bf16* src = Dw + (size_t)(n0 + r) * IDIM + kt2 * 64 + skk[j];
      GLDS16(src, bb + 32768 + h * 16384 + j * 8192 + ldsw);
    }
  };

  f32x4 acc[8][4];
#pragma unroll
  for (int m = 0; m < 8; ++m)
#pragma unroll
    for (int n = 0; n < 4; ++n)
#pragma unroll
      for (int j = 0; j < 4; ++j) acc[m][n][j] = 0.f;

  const int frow = lane & 15;
  const int q16  = (lane >> 4) * 16;
  const int NT   = IDIM / 64;   // 128

  {
    char* s0 = smem;
    char* s1 = smem + 65536;
    stageA(s0, 0, 0); stageB(s0, 0, 0); stageA(s0, 1, 0); stageB(s0, 1, 0);
    stageA(s1, 0, 1); stageB(s1, 0, 1);
  }
  WAITV(4); BAR();

  for (int kt = 0; kt < NT; ++kt) {
    const int b = kt & 1;
    char* sb = smem + b * 65536;
    char* so = smem + (b ^ 1) * 65536;
    bf16x8 aF[4][2], bF[2][2];

    // ---- phase 0: mh0 x nh0 ----
#pragma unroll
    for (int m = 0; m < 4; ++m) { int rp = wr * 64 + m * 16 + frow;
      aF[m][0] = RDF(sb, rp, 0); aF[m][1] = RDF(sb, rp, 1); }
#pragma unroll
    for (int n = 0; n < 2; ++n) { int rp = wc * 32 + n * 16 + frow;
      bF[n][0] = RDF(sb + 32768, rp, 0); bF[n][1] = RDF(sb + 32768, rp, 1); }
    if (kt + 1 < NT) stageA(so, 1, kt + 1);
    BAR();
    __builtin_amdgcn_s_setprio(1);
#pragma unroll
    for (int n = 0; n < 2; ++n)
#pragma unroll
      for (int m = 0; m < 4; ++m) {
        acc[m][n] = MFMA(aF[m][0], bF[n][0], acc[m][n]);
        acc[m][n] = MFMA(aF[m][1], bF[n][1], acc[m][n]);
      }
    __builtin_amdgcn_s_setprio(0);
    BAR();

    // ---- phase 1: mh0 x nh1 ----
#pragma unroll
    for (int n = 0; n < 2; ++n) { int rp = wc * 32 + n * 16 + frow;
      bF[n][0] = RDF(sb + 49152, rp, 0); bF[n][1] = RDF(sb + 49152, rp, 1); }
    if (kt + 1 < NT) stageB(so, 1, kt + 1);
    BAR();
    __builtin_amdgcn_s_setprio(1);
#pragma unroll
    for (int n = 0; n < 2; ++n)
#pragma unroll
      for (int m = 0; m < 4; ++m) {
        acc[m][2 + n] = MFMA(aF[m][0], bF[n][0], acc[m][2 + n]);
        acc[m][2 + n] = MFMA(aF[m][1], bF[n][1], acc[m][2 + n]);
      }
    __builtin_amdgcn_s_setprio(0);
    BAR();

    // ---- phase 2: mh1 x nh0 ----
#pragma unroll
    for (int m = 0; m < 4; ++m) { int rp = wr * 64 + m * 16 + frow;
      aF[m][0] = RDF(sb + 16384, rp, 0); aF[m][1] = RDF(sb + 16384, rp, 1); }
#pragma unroll
    for (int n = 0; n < 2; ++n) { int rp = wc * 32 + n * 16 + frow;
      bF[n][0] = RDF(sb + 32768, rp, 0); bF[n][1] = RDF(sb + 32768, rp, 1); }
    if (kt + 2 < NT) stageA(sb, 0, kt + 2);
    BAR();
    __builtin_amdgcn_s_setprio(1);
#pragma unroll
    for (int n = 0; n < 2; ++n)
#pragma unroll
      for (int m = 0; m < 4; ++m) {
        acc[4 + m][n] = MFMA(aF[m][0], bF[n][0], acc[4 + m][n]);
        acc[4 + m][n] = MFMA(aF[m][1], bF[n][1], acc[4 + m][n]);
      }
    __builtin_amdgcn_s_setprio(0);
    BAR();

    // ---- phase 3: mh1 x nh1 ----
#pragma unroll
    for (int n = 0; n < 2; ++n) { int rp = wc * 32 + n * 16 + frow;
      bF[n][0] = RDF(sb + 49152, rp, 0); bF[n][1] = RDF(sb + 49152, rp, 1); }
    if (kt + 2 < NT) stageB(sb, 0, kt + 2);
    BAR();
    __builtin_amdgcn_s_setprio(1);
#pragma unroll
    for (int n = 0; n < 2; ++n)
#pragma unroll
      for (int m = 0; m < 4; ++m) {
        acc[4 + m][2 + n] = MFMA(aF[m][0], bF[n][0], acc[4 + m][2 + n]);
        acc[4 + m][2 + n] = MFMA(aF[m][1], bF[n][1], acc[4 + m][2 + n]);
      }
    __builtin_amdgcn_s_setprio(0);
    if (kt < NT - 2) { WAITV(4); } else if (kt == NT - 2) { WAITV(0); }
    BAR();
  }

  const int orow0 = m0 + wr * 128 + (lane >> 4) * 4;
  const int ocol0 = blockIdx.y * 256 + wc * 64 + frow;
#pragma unroll
  for (int m = 0; m < 8; ++m)
#pragma unroll
    for (int n = 0; n < 4; ++n)
#pragma unroll
      for (int j = 0; j < 4; ++j)
        out[(size_t)(orow0 + m * 16 + j) * HDIM + (ocol0 + n * 16)] = acc[m][n][j];
}

// ===========================================================================
// Fallback: round-3 kernels (128^2 2-barrier, per-expert) if ws is small.
// ===========================================================================
__global__ __launch_bounds__(256) void gateup2_kernel(
    const __bf16* __restrict__ X, const __bf16* __restrict__ Gw,
    const __bf16* __restrict__ Uw, __bf16* __restrict__ act)
{
  __shared__ __bf16 lds[2][3][128 * 32];
  const int tid  = threadIdx.x;
  const int lane = tid & 63;
  const int wave = tid >> 6;
  const int wr = wave >> 1, wc = wave & 1;
  const int m0 = blockIdx.x * 128;
  const int n0 = blockIdx.y * 128;

  int srow[2], scol[2];
#pragma unroll
  for (int h = 0; h < 2; ++h) {
    const int B  = h * 4096 + tid * 16;
    const int Bs = B ^ (((B >> 7) & 3) << 4);
    srow[h] = Bs >> 6;
    scol[h] = (Bs & 63) >> 1;
  }
  const int ldst_off[2] = { wave * 1024, 4096 + wave * 1024 };

  f32x4 accg[4][4], accu[4][4];
#pragma unroll
  for (int m = 0; m < 4; ++m)
#pragma unroll
    for (int n = 0; n < 4; ++n)
#pragma unroll
      for (int j = 0; j < 4; ++j) { accg[m][n][j] = 0.f; accu[m][n][j] = 0.f; }

  const int frow  = lane & 15;
  const int rdoff = ((lane >> 4) * 16) ^ (((frow >> 1) & 3) << 4);

  auto stage = [&](int buf, int kt) {
    const int k0 = kt * 32;
#pragma unroll
    for (int h = 0; h < 2; ++h) {
      GLDS16(X  + (size_t)(m0 + srow[h]) * HDIM + k0 + scol[h], (char*)&lds[buf][0][0] + ldst_off[h]);
      GLDS16(Gw + (size_t)(n0 + srow[h]) * HDIM + k0 + scol[h], (char*)&lds[buf][1][0] + ldst_off[h]);
      GLDS16(Uw + (size_t)(n0 + srow[h]) * HDIM + k0 + scol[h], (char*)&lds[buf][2][0] + ldst_off[h]);
    }
  };

  const int NT = HDIM / 32;
  stage(0, 0);
  int cur = 0;
  for (int kt = 0; kt < NT; ++kt) {
    __syncthreads();
    if (kt + 1 < NT) stage(cur ^ 1, kt + 1);
    const char* bA = (const char*)&lds[cur][0][0];
    const char* bG = (const char*)&lds[cur][1][0];
    const char* bU = (const char*)&lds[cur][2][0];
    bf16x8 af[4];
#pragma unroll
    for (int m = 0; m < 4; ++m)
      af[m] = *(const bf16x8*)(bA + (wr * 64 + m * 16 + frow) * 64 + rdoff);
#pragma unroll
    for (int n = 0; n < 4; ++n) {
      bf16x8 bg = *(const bf16x8*)(bG + (wc * 64 + n * 16 + frow) * 64 + rdoff);
      bf16x8 bu = *(const bf16x8*)(bU + (wc * 64 + n * 16 + frow) * 64 + rdoff);
#pragma unroll
      for (int m = 0; m < 4; ++m) {
        accg[m][n] = MFMA(af[m], bg, accg[m][n]);
        accu[m][n] = MFMA(af[m], bu, accu[m][n]);
      }
    }
    cur ^= 1;
  }
  const int orow = m0 + wr * 64 + (lane >> 4) * 4;
  const int ocol = n0 + wc * 64 + (lane & 15);
#pragma unroll
  for (int m = 0; m < 4; ++m)
#pragma unroll
    for (int n = 0; n < 4; ++n)
#pragma unroll
      for (int j = 0; j < 4; ++j) {
        float g = accg[m][n][j];
        float u = accu[m][n][j];
        float s = g / (1.0f + __expf(-g));
        act[(size_t)(orow + m * 16 + j) * IDIM + (ocol + n * 16)] = (__bf16)(s * u);
      }
}

__global__ __launch_bounds__(256) void down2_kernel(
    const __bf16* __restrict__ act, const __bf16* __restrict__ Dw,
    float* __restrict__ out)
{
  __shared__ __bf16 lds[2][2][128 * 32];
  const int tid  = threadIdx.x;
  const int lane = tid & 63;
  const int wave = tid >> 6;
  const int wr = wave >> 1, wc = wave & 1;
  const int m0 = blockIdx.x * 128;
  const int n0 = blockIdx.y * 128;

  int srow[2], scol[2];
#pragma unroll
  for (int h = 0; h < 2; ++h) {
    const int B  = h * 4096 + tid * 16;
    const int Bs = B ^ (((B >> 7) & 3) << 4);
    srow[h] = Bs >> 6;
    scol[h] = (Bs & 63) >> 1;
  }
  const int ldst_off[2] = { wave * 1024, 4096 + wave * 1024 };

  f32x4 acc[4][4];
#pragma unroll
  for (int m = 0; m < 4; ++m)
#pragma unroll
    for (int n = 0; n < 4; ++n)
#pragma unroll
      for (int j = 0; j < 4; ++j) acc[m][n][j] = 0.f;

  const int frow  = lane & 15;
  const int rdoff = ((lane >> 4) * 16) ^ (((frow >> 1) & 3) << 4);

  auto stage = [&](int buf, int kt) {
    const int k0 = kt * 32;
#pragma unroll
    for (int h = 0; h < 2; ++h) {
      GLDS16(act + (size_t)(m0 + srow[h]) * IDIM + k0 + scol[h], (char*)&lds[buf][0][0] + ldst_off[h]);
      GLDS16(Dw  + (size_t)(n0 + srow[h]) * IDIM + k0 + scol[h], (char*)&lds[buf][1][0] + ldst_off[h]);
    }
  };

  const int NT = IDIM / 32;
  stage(0, 0);
  int cur = 0;
  for (int kt = 0; kt < NT; ++kt) {
    __syncthreads();
    if (kt + 1 < NT) stage(cur ^ 1, kt + 1);
    const char* bA = (const char*)&lds[cur][0][0];
    const char* bW = (const char*)&lds[cur][1][0];
    bf16x8 af[4];
#pragma unroll
    for (int m = 0; m < 4; ++m)
      af[m] = *(const bf16x8*)(bA + (wr * 64 + m * 16 + frow) * 64 + rdoff);
#pragma unroll
    for (int n = 0; n < 4; ++n) {
      bf16x8 bw = *(const bf16x8*)(bW + (wc * 64 + n * 16 + frow) * 64 + rdoff);
#pragma unroll
      for (int m = 0; m < 4; ++m)
        acc[m][n] = MFMA(af[m], bw, acc[m][n]);
    }
    cur ^= 1;
  }
  const int orow = m0 + wr * 64 + (lane >> 4) * 4;
  const int ocol = n0 + wc * 64 + (lane & 15);
#pragma unroll
  for (int m = 0; m < 4; ++m)
#pragma unroll
    for (int n = 0; n < 4; ++n)
#pragma unroll
      for (int j = 0; j < 4; ++j)
        out[(size_t)(orow + m * 16 + j) * HDIM + (ocol + n * 16)] = acc[m][n][j];
}

// ---------------------------------------------------------------------------
extern "C" void kernel_launch(void* const* d_in, const int* in_sizes, int n_in,
                              void* d_out, int out_size, void* d_ws, size_t ws_size,
                              hipStream_t stream)
{
  const float* hidden = (const float*)d_in[0];
  const float* gate_w = (const float*)d_in[1];
  const float* up_w   = (const float*)d_in[2];
  const float* down_w = (const float*)d_in[3];
  float* out = (float*)d_out;

  const size_t SZ_X    = (size_t)32768 * HDIM;           // 67.1M elems
  const size_t SZ_Wall = (size_t)E_NUM * IDIM * HDIM;    // 134.2M elems
  const size_t SZ_ACT  = (size_t)32768 * IDIM;           // 268.4M elems
  const size_t need8 = (SZ_X + 3 * SZ_Wall + SZ_ACT) * sizeof(__bf16);  // ~1.48 GB

  if (ws_size >= need8) {
    __bf16* xb  = (__bf16*)d_ws;
    __bf16* gwb = xb  + SZ_X;
    __bf16* uwb = gwb + SZ_Wall;
    __bf16* dwb = uwb + SZ_Wall;
    __bf16* actb = dwb + SZ_Wall;

    cvt_kernel<<<SZ_X    / 2048, 256, 0, stream>>>(hidden, xb);
    cvt_kernel<<<SZ_Wall / 2048, 256, 0, stream>>>(gate_w, gwb);
    cvt_kernel<<<SZ_Wall / 2048, 256, 0, stream>>>(up_w,   uwb);
    cvt_kernel<<<SZ_Wall / 2048, 256, 0, stream>>>(down_w, dwb);

    gateup8_kernel<<<dim3(CHUNK / 256, IDIM / 128, E_NUM), 512, 131072, stream>>>(xb, gwb, uwb, actb);
    down8_kernel  <<<dim3(CHUNK / 256, HDIM / 256, E_NUM), 512, 131072, stream>>>(actb, dwb, out);
  } else {
    // round-3 fallback: per-expert cvt + 128^2 2-barrier kernels
    const size_t sX = (size_t)CHUNK * HDIM;
    const size_t sW = (size_t)IDIM * HDIM;
    const size_t sA = (size_t)CHUNK * IDIM;
    __bf16* xb = (__bf16*)d_ws;
    __bf16* gb = xb + sX;
    __bf16* ub = gb + sW;
    __bf16* db = ub + sW;
    __bf16* act = db + sW;
    for (int e = 0; e < E_NUM; ++e) {
      const float* Xe = hidden + (size_t)e * sX;
      const float* Ge = gate_w + (size_t)e * sW;
      const float* Ue = up_w   + (size_t)e * sW;
      const float* De = down_w + (size_t)e * sW;
      float* Oe = out + (size_t)e * CHUNK * HDIM;
      cvt_kernel<<<sX / 2048, 256, 0, stream>>>(Xe, xb);
      cvt_kernel<<<sW / 2048, 256, 0, stream>>>(Ge, gb);
      cvt_kernel<<<sW / 2048, 256, 0, stream>>>(Ue, ub);
      cvt_kernel<<<sW / 2048, 256, 0, stream>>>(De, db);
      gateup2_kernel<<<dim3(CHUNK / 128, IDIM / 128), 256, 0, stream>>>(xb, gb, ub, act);
      down2_kernel<<<dim3(CHUNK / 128, HDIM / 128), 256, 0, stream>>>(act, db, Oe);
    }
  }
}

// Round 5
// 3394.921 us; speedup vs baseline: 2.7459x; 1.0981x over previous
//
#include <hip/hip_runtime.h>
#include <hip/hip_bf16.h>
#include <stdint.h>

// Problem constants (fixed by setup_inputs)
#define E_NUM 8
#define CHUNK 4096
#define HDIM  2048
#define IDIM  8192

typedef __bf16 bf16x8 __attribute__((ext_vector_type(8)));
typedef __bf16 bf16x4 __attribute__((ext_vector_type(4)));
typedef float  f32x4  __attribute__((ext_vector_type(4)));

#define GLDS16(g, l) __builtin_amdgcn_global_load_lds(                         \
    (const __attribute__((address_space(1))) void*)(g),                        \
    (__attribute__((address_space(3))) void*)(l), 16, 0, 0)
#define MFMA(a, b, c) __builtin_amdgcn_mfma_f32_16x16x32_bf16((a), (b), (c), 0, 0, 0)
#define FENCE() asm volatile("" ::: "memory")
#define BAR()   do { FENCE(); __builtin_amdgcn_s_barrier(); FENCE(); } while (0)
#define WAITV(n) asm volatile("s_waitcnt vmcnt(" #n ")" ::: "memory")

// frag read from a 128-row x 128B LDS region; 3-bit XOR swizzle (G4 fix):
// 8 slots/row (bits 4-6) XOR row bits 0-2 -> 16-lane row-sweep = conflict-free
#define RDF(base, rp, ks) \
  (*(const bf16x8*)((base) + (rp) * 128 + ((((ks) * 64) + q16) ^ (((rp) & 7) << 4))))

// ---------------------------------------------------------------------------
// f32 -> bf16 conversion (memory-bound, 8 elems/thread)
// ---------------------------------------------------------------------------
__global__ __launch_bounds__(256) void cvt_kernel(
    const float* __restrict__ src, __bf16* __restrict__ dst)
{
  const size_t i = ((size_t)blockIdx.x * 256 + threadIdx.x) * 8;
  float4 a = *reinterpret_cast<const float4*>(src + i);
  float4 b = *reinterpret_cast<const float4*>(src + i + 4);
  bf16x8 r;
  r[0] = (__bf16)a.x; r[1] = (__bf16)a.y; r[2] = (__bf16)a.z; r[3] = (__bf16)a.w;
  r[4] = (__bf16)b.x; r[5] = (__bf16)b.y; r[6] = (__bf16)b.z; r[7] = (__bf16)b.w;
  *reinterpret_cast<bf16x8*>(dst + i) = r;
}

// ===========================================================================
// 8-phase fused gate+up GEMM.  BM=256 (tokens) x BN=128 (cols of BOTH g,u),
// BK=64. 8 waves as 4M x 2N; per-wave 64x64 per matrix.
// LDS per buffer (64KB): Ah0@0, Ah1@16K, G@32K, U@48K (each 128 rows x 128B).
// Grid: x = n-blocks (fastest -> weight panel L3-resident), y = m-blocks, z = e.
// ===========================================================================
__global__ __launch_bounds__(512, 2) void gateup8_kernel(
    const __bf16* __restrict__ X, const __bf16* __restrict__ Gw,
    const __bf16* __restrict__ Uw, __bf16* __restrict__ act)
{
  extern __shared__ char smem[];   // 2 x 64KB
  const int tid  = threadIdx.x;
  const int lane = tid & 63;
  const int wave = tid >> 6;
  const int wm = wave >> 1, wn = wave & 1;
  const int e  = blockIdx.z;
  const int m0 = e * CHUNK + blockIdx.y * 256;   // row into X/act
  const int n0 = e * IDIM  + blockIdx.x * 128;   // row into Gw/Uw

  // staging precompute: linear dest byte P -> pre-swizzled source (row,col)
  int su[2], skk[2];
#pragma unroll
  for (int j = 0; j < 2; ++j) {
    int P = j * 8192 + tid * 16;
    int L = P ^ (((P >> 7) & 7) << 4);   // same 3-bit involution as RDF
    su[j]  = L >> 7;          // row-in-region 0..127
    skk[j] = (L & 127) >> 1;  // k elem offset (multiple of 8 -> 16B aligned)
  }
  const int ldsw = wave * 1024;  // wave-uniform dest offset within 8KB chunk

  auto stageA = [&](char* bb, int h, int kt2) {
#pragma unroll
    for (int j = 0; j < 2; ++j) {
      int u = su[j];
      int r = (u & 31) + h * 32 + (u >> 5) * 64;
      const __bf16* src = X + (size_t)(m0 + r) * HDIM + kt2 * 64 + skk[j];
      GLDS16(src, bb + h * 16384 + j * 8192 + ldsw);
    }
  };
  auto stageW = [&](char* bb, int w, int kt2) {   // w: 0=G, 1=U
    const __bf16* W = w ? Uw : Gw;
#pragma unroll
    for (int j = 0; j < 2; ++j) {
      const __bf16* src = W + (size_t)(n0 + su[j]) * HDIM + kt2 * 64 + skk[j];
      GLDS16(src, bb + 32768 + w * 16384 + j * 8192 + ldsw);
    }
  };

  f32x4 accg[4][4], accu[4][4];
#pragma unroll
  for (int m = 0; m < 4; ++m)
#pragma unroll
    for (int n = 0; n < 4; ++n)
#pragma unroll
      for (int j = 0; j < 4; ++j) { accg[m][n][j] = 0.f; accu[m][n][j] = 0.f; }

  const int frow = lane & 15;
  const int q16  = (lane >> 4) * 16;
  const int NT   = HDIM / 64;   // 32

  // prologue: tile0 {Ah0,G,Ah1,U}, tile1 {Ah0,G}; then drain to 2 units
  {
    char* s0 = smem;
    char* s1 = smem + 65536;
    stageA(s0, 0, 0); stageW(s0, 0, 0); stageA(s0, 1, 0); stageW(s0, 1, 0);
    stageA(s1, 0, 1); stageW(s1, 0, 1);
  }
  WAITV(4); BAR();

  for (int kt = 0; kt < NT; ++kt) {
    const int b = kt & 1;
    char* sb = smem + b * 65536;
    char* so = smem + (b ^ 1) * 65536;
    bf16x8 aF[2][2], wF[4][2];

    // ---- phase 0: g, mh0 ----
#pragma unroll
    for (int m = 0; m < 2; ++m) { int rp = wm * 32 + m * 16 + frow;
      aF[m][0] = RDF(sb, rp, 0); aF[m][1] = RDF(sb, rp, 1); }
#pragma unroll
    for (int n = 0; n < 4; ++n) { int rp = wn * 64 + n * 16 + frow;
      wF[n][0] = RDF(sb + 32768, rp, 0); wF[n][1] = RDF(sb + 32768, rp, 1); }
    if (kt + 1 < NT) stageA(so, 1, kt + 1);
    BAR();
    __builtin_amdgcn_s_setprio(1);
#pragma unroll
    for (int n = 0; n < 4; ++n)
#pragma unroll
      for (int m = 0; m < 2; ++m) {
        accg[m][n] = MFMA(aF[m][0], wF[n][0], accg[m][n]);
        accg[m][n] = MFMA(aF[m][1], wF[n][1], accg[m][n]);
      }
    __builtin_amdgcn_s_setprio(0);
    BAR();

    // ---- phase 1: u, mh0 (A frags reused) ----
#pragma unroll
    for (int n = 0; n < 4; ++n) { int rp = wn * 64 + n * 16 + frow;
      wF[n][0] = RDF(sb + 49152, rp, 0); wF[n][1] = RDF(sb + 49152, rp, 1); }
    if (kt + 1 < NT) stageW(so, 1, kt + 1);
    BAR();
    __builtin_amdgcn_s_setprio(1);
#pragma unroll
    for (int n = 0; n < 4; ++n)
#pragma unroll
      for (int m = 0; m < 2; ++m) {
        accu[m][n] = MFMA(aF[m][0], wF[n][0], accu[m][n]);
        accu[m][n] = MFMA(aF[m][1], wF[n][1], accu[m][n]);
      }
    __builtin_amdgcn_s_setprio(0);
    BAR();

    // ---- phase 2: g, mh1 ----
#pragma unroll
    for (int m = 0; m < 2; ++m) { int rp = wm * 32 + m * 16 + frow;
      aF[m][0] = RDF(sb + 16384, rp, 0); aF[m][1] = RDF(sb + 16384, rp, 1); }
#pragma unroll
    for (int n = 0; n < 4; ++n) { int rp = wn * 64 + n * 16 + frow;
      wF[n][0] = RDF(sb + 32768, rp, 0); wF[n][1] = RDF(sb + 32768, rp, 1); }
    if (kt + 2 < NT) stageA(sb, 0, kt + 2);
    BAR();
    __builtin_amdgcn_s_setprio(1);
#pragma unroll
    for (int n = 0; n < 4; ++n)
#pragma unroll
      for (int m = 0; m < 2; ++m) {
        accg[2 + m][n] = MFMA(aF[m][0], wF[n][0], accg[2 + m][n]);
        accg[2 + m][n] = MFMA(aF[m][1], wF[n][1], accg[2 + m][n]);
      }
    __builtin_amdgcn_s_setprio(0);
    BAR();

    // ---- phase 3: u, mh1 ----
#pragma unroll
    for (int n = 0; n < 4; ++n) { int rp = wn * 64 + n * 16 + frow;
      wF[n][0] = RDF(sb + 49152, rp, 0); wF[n][1] = RDF(sb + 49152, rp, 1); }
    if (kt + 2 < NT) stageW(sb, 0, kt + 2);
    BAR();
    __builtin_amdgcn_s_setprio(1);
#pragma unroll
    for (int n = 0; n < 4; ++n)
#pragma unroll
      for (int m = 0; m < 2; ++m) {
        accu[2 + m][n] = MFMA(aF[m][0], wF[n][0], accu[2 + m][n]);
        accu[2 + m][n] = MFMA(aF[m][1], wF[n][1], accu[2 + m][n]);
      }
    __builtin_amdgcn_s_setprio(0);
    if (kt < NT - 2) { WAITV(4); } else if (kt == NT - 2) { WAITV(0); }
    BAR();
  }

  // epilogue: silu(g)*u -> bf16 act
  const int orow0 = m0 + wm * 64 + (lane >> 4) * 4;
  const int ocol0 = blockIdx.x * 128 + wn * 64 + frow;
#pragma unroll
  for (int m = 0; m < 4; ++m)
#pragma unroll
    for (int n = 0; n < 4; ++n)
#pragma unroll
      for (int j = 0; j < 4; ++j) {
        float g = accg[m][n][j];
        float u = accu[m][n][j];
        float s = g / (1.0f + __expf(-g));
        act[(size_t)(orow0 + m * 16 + j) * IDIM + (ocol0 + n * 16)] = (__bf16)(s * u);
      }
}

// ===========================================================================
// 8-phase down GEMM (grouped over experts): out = act . Dw^T  (f32 out)
// BM=BN=256, BK=64. 8 waves as 2M x 4N; per-wave 128x64; acc[8][4].
// Grid: x = n-blocks (fastest -> Dw panel resident), y = m-blocks, z = e.
// ===========================================================================
__global__ __launch_bounds__(512, 2) void down8_kernel(
    const __bf16* __restrict__ act, const __bf16* __restrict__ Dw,
    float* __restrict__ out)
{
  extern __shared__ char smem[];
  const int tid  = threadIdx.x;
  const int lane = tid & 63;
  const int wave = tid >> 6;
  const int wr = wave >> 2, wc = wave & 3;
  const int e  = blockIdx.z;
  const int m0 = e * CHUNK + blockIdx.y * 256;   // row into act/out
  const int n0 = e * HDIM  + blockIdx.x * 256;   // row into Dw

  int su[2], skk[2];
#pragma unroll
  for (int j = 0; j < 2; ++j) {
    int P = j * 8192 + tid * 16;
    int L = P ^ (((P >> 7) & 7) << 4);
    su[j]  = L >> 7;
    skk[j] = (L & 127) >> 1;
  }
  const int ldsw = wave * 1024;

  auto stageA = [&](char* bb, int h, int kt2) {
#pragma unroll
    for (int j = 0; j < 2; ++j) {
      int u = su[j];
      int r = (u & 63) + h * 64 + (u >> 6) * 128;
      const __bf16* src = act + (size_t)(m0 + r) * IDIM + kt2 * 64 + skk[j];
      GLDS16(src, bb + h * 16384 + j * 8192 + ldsw);
    }
  };
  auto stageB = [&](char* bb, int h, int kt2) {
#pragma unroll
    for (int j = 0; j < 2; ++j) {
      int u = su[j];
      int r = (u & 31) + h * 32 + (u >> 5) * 64;
      const __bf16* src = Dw + (size_t)(n0 + r) * IDIM + kt2 * 64 + skk[j];
      GLDS16(src, bb + 32768 + h * 16384 + j * 8192 + ldsw);
    }
  };

  f32x4 acc[8][4];
#pragma unroll
  for (int m = 0; m < 8; ++m)
#pragma unroll
    for (int n = 0; n < 4; ++n)
#pragma unroll
      for (int j = 0; j < 4; ++j) acc[m][n][j] = 0.f;

  const int frow = lane & 15;
  const int q16  = (lane >> 4) * 16;
  const int NT   = IDIM / 64;   // 128

  {
    char* s0 = smem;
    char* s1 = smem + 65536;
    stageA(s0, 0, 0); stageB(s0, 0, 0); stageA(s0, 1, 0); stageB(s0, 1, 0);
    stageA(s1, 0, 1); stageB(s1, 0, 1);
  }
  WAITV(4); BAR();

  for (int kt = 0; kt < NT; ++kt) {
    const int b = kt & 1;
    char* sb = smem + b * 65536;
    char* so = smem + (b ^ 1) * 65536;
    bf16x8 aF[4][2], bF[2][2];

    // ---- phase 0: mh0 x nh0 ----
#pragma unroll
    for (int m = 0; m < 4; ++m) { int rp = wr * 64 + m * 16 + frow;
      aF[m][0] = RDF(sb, rp, 0); aF[m][1] = RDF(sb, rp, 1); }
#pragma unroll
    for (int n = 0; n < 2; ++n) { int rp = wc * 32 + n * 16 + frow;
      bF[n][0] = RDF(sb + 32768, rp, 0); bF[n][1] = RDF(sb + 32768, rp, 1); }
    if (kt + 1 < NT) stageA(so, 1, kt + 1);
    BAR();
    __builtin_amdgcn_s_setprio(1);
#pragma unroll
    for (int n = 0; n < 2; ++n)
#pragma unroll
      for (int m = 0; m < 4; ++m) {
        acc[m][n] = MFMA(aF[m][0], bF[n][0], acc[m][n]);
        acc[m][n] = MFMA(aF[m][1], bF[n][1], acc[m][n]);
      }
    __builtin_amdgcn_s_setprio(0);
    BAR();

    // ---- phase 1: mh0 x nh1 ----
#pragma unroll
    for (int n = 0; n < 2; ++n) { int rp = wc * 32 + n * 16 + frow;
      bF[n][0] = RDF(sb + 49152, rp, 0); bF[n][1] = RDF(sb + 49152, rp, 1); }
    if (kt + 1 < NT) stageB(so, 1, kt + 1);
    BAR();
    __builtin_amdgcn_s_setprio(1);
#pragma unroll
    for (int n = 0; n < 2; ++n)
#pragma unroll
      for (int m = 0; m < 4; ++m) {
        acc[m][2 + n] = MFMA(aF[m][0], bF[n][0], acc[m][2 + n]);
        acc[m][2 + n] = MFMA(aF[m][1], bF[n][1], acc[m][2 + n]);
      }
    __builtin_amdgcn_s_setprio(0);
    BAR();

    // ---- phase 2: mh1 x nh0 ----
#pragma unroll
    for (int m = 0; m < 4; ++m) { int rp = wr * 64 + m * 16 + frow;
      aF[m][0] = RDF(sb + 16384, rp, 0); aF[m][1] = RDF(sb + 16384, rp, 1); }
#pragma unroll
    for (int n = 0; n < 2; ++n) { int rp = wc * 32 + n * 16 + frow;
      bF[n][0] = RDF(sb + 32768, rp, 0); bF[n][1] = RDF(sb + 32768, rp, 1); }
    if (kt + 2 < NT) stageA(sb, 0, kt + 2);
    BAR();
    __builtin_amdgcn_s_setprio(1);
#pragma unroll
    for (int n = 0; n < 2; ++n)
#pragma unroll
      for (int m = 0; m < 4; ++m) {
        acc[4 + m][n] = MFMA(aF[m][0], bF[n][0], acc[4 + m][n]);
        acc[4 + m][n] = MFMA(aF[m][1], bF[n][1], acc[4 + m][n]);
      }
    __builtin_amdgcn_s_setprio(0);
    BAR();

    // ---- phase 3: mh1 x nh1 ----
#pragma unroll
    for (int n = 0; n < 2; ++n) { int rp = wc * 32 + n * 16 + frow;
      bF[n][0] = RDF(sb + 49152, rp, 0); bF[n][1] = RDF(sb + 49152, rp, 1); }
    if (kt + 2 < NT) stageB(sb, 0, kt + 2);
    BAR();
    __builtin_amdgcn_s_setprio(1);
#pragma unroll
    for (int n = 0; n < 2; ++n)
#pragma unroll
      for (int m = 0; m < 4; ++m) {
        acc[4 + m][2 + n] = MFMA(aF[m][0], bF[n][0], acc[4 + m][2 + n]);
        acc[4 + m][2 + n] = MFMA(aF[m][1], bF[n][1], acc[4 + m][2 + n]);
      }
    __builtin_amdgcn_s_setprio(0);
    if (kt < NT - 2) { WAITV(4); } else if (kt == NT - 2) { WAITV(0); }
    BAR();
  }

  const int orow0 = m0 + wr * 128 + (lane >> 4) * 4;
  const int ocol0 = blockIdx.x * 256 + wc * 64 + frow;
#pragma unroll
  for (int m = 0; m < 8; ++m)
#pragma unroll
    for (int n = 0; n < 4; ++n)
#pragma unroll
      for (int j = 0; j < 4; ++j)
        out[(size_t)(orow0 + m * 16 + j) * HDIM + (ocol0 + n * 16)] = acc[m][n][j];
}

// ===========================================================================
// Fallback: round-3 kernels (128^2 2-barrier, per-expert) if ws is small.
// ===========================================================================
__global__ __launch_bounds__(256) void gateup2_kernel(
    const __bf16* __restrict__ X, const __bf16* __restrict__ Gw,
    const __bf16* __restrict__ Uw, __bf16* __restrict__ act)
{
  __shared__ __bf16 lds[2][3][128 * 32];
  const int tid  = threadIdx.x;
  const int lane = tid & 63;
  const int wave = tid >> 6;
  const int wr = wave >> 1, wc = wave & 1;
  const int m0 = blockIdx.x * 128;
  const int n0 = blockIdx.y * 128;

  int srow[2], scol[2];
#pragma unroll
  for (int h = 0; h < 2; ++h) {
    const int B  = h * 4096 + tid * 16;
    const int Bs = B ^ (((B >> 7) & 3) << 4);
    srow[h] = Bs >> 6;
    scol[h] = (Bs & 63) >> 1;
  }
  const int ldst_off[2] = { wave * 1024, 4096 + wave * 1024 };

  f32x4 accg[4][4], accu[4][4];
#pragma unroll
  for (int m = 0; m < 4; ++m)
#pragma unroll
    for (int n = 0; n < 4; ++n)
#pragma unroll
      for (int j = 0; j < 4; ++j) { accg[m][n][j] = 0.f; accu[m][n][j] = 0.f; }

  const int frow  = lane & 15;
  const int rdoff = ((lane >> 4) * 16) ^ (((frow >> 1) & 3) << 4);

  auto stage = [&](int buf, int kt) {
    const int k0 = kt * 32;
#pragma unroll
    for (int h = 0; h < 2; ++h) {
      GLDS16(X  + (size_t)(m0 + srow[h]) * HDIM + k0 + scol[h], (char*)&lds[buf][0][0] + ldst_off[h]);
      GLDS16(Gw + (size_t)(n0 + srow[h]) * HDIM + k0 + scol[h], (char*)&lds[buf][1][0] + ldst_off[h]);
      GLDS16(Uw + (size_t)(n0 + srow[h]) * HDIM + k0 + scol[h], (char*)&lds[buf][2][0] + ldst_off[h]);
    }
  };

  const int NT = HDIM / 32;
  stage(0, 0);
  int cur = 0;
  for (int kt = 0; kt < NT; ++kt) {
    __syncthreads();
    if (kt + 1 < NT) stage(cur ^ 1, kt + 1);
    const char* bA = (const char*)&lds[cur][0][0];
    const char* bG = (const char*)&lds[cur][1][0];
    const char* bU = (const char*)&lds[cur][2][0];
    bf16x8 af[4];
#pragma unroll
    for (int m = 0; m < 4; ++m)
      af[m] = *(const bf16x8*)(bA + (wr * 64 + m * 16 + frow) * 64 + rdoff);
#pragma unroll
    for (int n = 0; n < 4; ++n) {
      bf16x8 bg = *(const bf16x8*)(bG + (wc * 64 + n * 16 + frow) * 64 + rdoff);
      bf16x8 bu = *(const bf16x8*)(bU + (wc * 64 + n * 16 + frow) * 64 + rdoff);
#pragma unroll
      for (int m = 0; m < 4; ++m) {
        accg[m][n] = MFMA(af[m], bg, accg[m][n]);
        accu[m][n] = MFMA(af[m], bu, accu[m][n]);
      }
    }
    cur ^= 1;
  }
  const int orow = m0 + wr * 64 + (lane >> 4) * 4;
  const int ocol = n0 + wc * 64 + (lane & 15);
#pragma unroll
  for (int m = 0; m < 4; ++m)
#pragma unroll
    for (int n = 0; n < 4; ++n)
#pragma unroll
      for (int j = 0; j < 4; ++j) {
        float g = accg[m][n][j];
        float u = accu[m][n][j];
        float s = g / (1.0f + __expf(-g));
        act[(size_t)(orow + m * 16 + j) * IDIM + (ocol + n * 16)] = (__bf16)(s * u);
      }
}

__global__ __launch_bounds__(256) void down2_kernel(
    const __bf16* __restrict__ act, const __bf16* __restrict__ Dw,
    float* __restrict__ out)
{
  __shared__ __bf16 lds[2][2][128 * 32];
  const int tid  = threadIdx.x;
  const int lane = tid & 63;
  const int wave = tid >> 6;
  const int wr = wave >> 1, wc = wave & 1;
  const int m0 = blockIdx.x * 128;
  const int n0 = blockIdx.y * 128;

  int srow[2], scol[2];
#pragma unroll
  for (int h = 0; h < 2; ++h) {
    const int B  = h * 4096 + tid * 16;
    const int Bs = B ^ (((B >> 7) & 3) << 4);
    srow[h] = Bs >> 6;
    scol[h] = (Bs & 63) >> 1;
  }
  const int ldst_off[2] = { wave * 1024, 4096 + wave * 1024 };

  f32x4 acc[4][4];
#pragma unroll
  for (int m = 0; m < 4; ++m)
#pragma unroll
    for (int n = 0; n < 4; ++n)
#pragma unroll
      for (int j = 0; j < 4; ++j) acc[m][n][j] = 0.f;

  const int frow  = lane & 15;
  const int rdoff = ((lane >> 4) * 16) ^ (((frow >> 1) & 3) << 4);

  auto stage = [&](int buf, int kt) {
    const int k0 = kt * 32;
#pragma unroll
    for (int h = 0; h < 2; ++h) {
      GLDS16(act + (size_t)(m0 + srow[h]) * IDIM + k0 + scol[h], (char*)&lds[buf][0][0] + ldst_off[h]);
      GLDS16(Dw  + (size_t)(n0 + srow[h]) * IDIM + k0 + scol[h], (char*)&lds[buf][1][0] + ldst_off[h]);
    }
  };

  const int NT = IDIM / 32;
  stage(0, 0);
  int cur = 0;
  for (int kt = 0; kt < NT; ++kt) {
    __syncthreads();
    if (kt + 1 < NT) stage(cur ^ 1, kt + 1);
    const char* bA = (const char*)&lds[cur][0][0];
    const char* bW = (const char*)&lds[cur][1][0];
    bf16x8 af[4];
#pragma unroll
    for (int m = 0; m < 4; ++m)
      af[m] = *(const bf16x8*)(bA + (wr * 64 + m * 16 + frow) * 64 + rdoff);
#pragma unroll
    for (int n = 0; n < 4; ++n) {
      bf16x8 bw = *(const bf16x8*)(bW + (wc * 64 + n * 16 + frow) * 64 + rdoff);
#pragma unroll
      for (int m = 0; m < 4; ++m)
        acc[m][n] = MFMA(af[m], bw, acc[m][n]);
    }
    cur ^= 1;
  }
  const int orow = m0 + wr * 64 + (lane >> 4) * 4;
  const int ocol = n0 + wc * 64 + (lane & 15);
#pragma unroll
  for (int m = 0; m < 4; ++m)
#pragma unroll
    for (int n = 0; n < 4; ++n)
#pragma unroll
      for (int j = 0; j < 4; ++j)
        out[(size_t)(orow + m * 16 + j) * HDIM + (ocol + n * 16)] = acc[m][n][j];
}

// ---------------------------------------------------------------------------
extern "C" void kernel_launch(void* const* d_in, const int* in_sizes, int n_in,
                              void* d_out, int out_size, void* d_ws, size_t ws_size,
                              hipStream_t stream)
{
  const float* hidden = (const float*)d_in[0];
  const float* gate_w = (const float*)d_in[1];
  const float* up_w   = (const float*)d_in[2];
  const float* down_w = (const float*)d_in[3];
  float* out = (float*)d_out;

  const size_t SZ_X    = (size_t)32768 * HDIM;           // 67.1M elems
  const size_t SZ_Wall = (size_t)E_NUM * IDIM * HDIM;    // 134.2M elems
  const size_t SZ_ACT  = (size_t)32768 * IDIM;           // 268.4M elems
  const size_t need8 = (SZ_X + 3 * SZ_Wall + SZ_ACT) * sizeof(__bf16);  // ~1.48 GB

  if (ws_size >= need8) {
    __bf16* xb  = (__bf16*)d_ws;
    __bf16* gwb = xb  + SZ_X;
    __bf16* uwb = gwb + SZ_Wall;
    __bf16* dwb = uwb + SZ_Wall;
    __bf16* actb = dwb + SZ_Wall;

    cvt_kernel<<<SZ_X    / 2048, 256, 0, stream>>>(hidden, xb);
    cvt_kernel<<<SZ_Wall / 2048, 256, 0, stream>>>(gate_w, gwb);
    cvt_kernel<<<SZ_Wall / 2048, 256, 0, stream>>>(up_w,   uwb);
    cvt_kernel<<<SZ_Wall / 2048, 256, 0, stream>>>(down_w, dwb);

    // x = n-blocks fastest: weight panels stay L3-resident, X/act stream
    gateup8_kernel<<<dim3(IDIM / 128, CHUNK / 256, E_NUM), 512, 131072, stream>>>(xb, gwb, uwb, actb);
    down8_kernel  <<<dim3(HDIM / 256, CHUNK / 256, E_NUM), 512, 131072, stream>>>(actb, dwb, out);
  } else {
    // round-3 fallback: per-expert cvt + 128^2 2-barrier kernels
    const size_t sX = (size_t)CHUNK * HDIM;
    const size_t sW = (size_t)IDIM * HDIM;
    __bf16* xb = (__bf16*)d_ws;
    __bf16* gb = xb + sX;
    __bf16* ub = gb + sW;
    __bf16* db = ub + sW;
    __bf16* act = db + sW;
    for (int e = 0; e < E_NUM; ++e) {
      const float* Xe = hidden + (size_t)e * sX;
      const float* Ge = gate_w + (size_t)e * sW;
      const float* Ue = up_w   + (size_t)e * sW;
      const float* De = down_w + (size_t)e * sW;
      float* Oe = out + (size_t)e * CHUNK * HDIM;
      cvt_kernel<<<sX / 2048, 256, 0, stream>>>(Xe, xb);
      cvt_kernel<<<sW / 2048, 256, 0, stream>>>(Ge, gb);
      cvt_kernel<<<sW / 2048, 256, 0, stream>>>(Ue, ub);
      cvt_kernel<<<sW / 2048, 256, 0, stream>>>(De, db);
      gateup2_kernel<<<dim3(CHUNK / 128, IDIM / 128), 256, 0, stream>>>(xb, gb, ub, act);
      down2_kernel<<<dim3(CHUNK / 128, HDIM / 128), 256, 0, stream>>>(act, db, Oe);
    }
  }
}

// Round 6
// 3242.080 us; speedup vs baseline: 2.8754x; 1.0471x over previous
//
#include <hip/hip_runtime.h>
#include <hip/hip_bf16.h>
#include <stdint.h>

// Problem constants (fixed by setup_inputs)
#define E_NUM 8
#define CHUNK 4096
#define HDIM  2048
#define IDIM  8192

typedef __bf16 bf16x8 __attribute__((ext_vector_type(8)));
typedef __bf16 bf16x4 __attribute__((ext_vector_type(4)));
typedef float  f32x4  __attribute__((ext_vector_type(4)));

#define GLDS16(g, l) __builtin_amdgcn_global_load_lds(                         \
    (const __attribute__((address_space(1))) void*)(g),                        \
    (__attribute__((address_space(3))) void*)(l), 16, 0, 0)
#define MFMA(a, b, c) __builtin_amdgcn_mfma_f32_16x16x32_bf16((a), (b), (c), 0, 0, 0)
#define FENCE() asm volatile("" ::: "memory")
#define BAR()   do { FENCE(); __builtin_amdgcn_s_barrier(); FENCE(); } while (0)
#define WAITV(n) asm volatile("s_waitcnt vmcnt(" #n ")" ::: "memory")

// frag read from a 128-row x 128B LDS region; 3-bit XOR swizzle:
// 8 slots/row (bits 4-6) XOR row bits 0-2 -> 16-lane row-sweep = conflict-free
#define RDF(base, rp, ks) \
  (*(const bf16x8*)((base) + (rp) * 128 + ((((ks) * 64) + q16) ^ (((rp) & 7) << 4))))

// ---------------------------------------------------------------------------
// f32 -> bf16 conversion (memory-bound, 8 elems/thread)
// ---------------------------------------------------------------------------
__global__ __launch_bounds__(256) void cvt_kernel(
    const float* __restrict__ src, __bf16* __restrict__ dst)
{
  const size_t i = ((size_t)blockIdx.x * 256 + threadIdx.x) * 8;
  float4 a = *reinterpret_cast<const float4*>(src + i);
  float4 b = *reinterpret_cast<const float4*>(src + i + 4);
  bf16x8 r;
  r[0] = (__bf16)a.x; r[1] = (__bf16)a.y; r[2] = (__bf16)a.z; r[3] = (__bf16)a.w;
  r[4] = (__bf16)b.x; r[5] = (__bf16)b.y; r[6] = (__bf16)b.z; r[7] = (__bf16)b.w;
  *reinterpret_cast<bf16x8*>(dst + i) = r;
}

// ===========================================================================
// 8-phase fused gate+up GEMM.  BM=256 x BN=128, BK=64. 8 waves (4M x 2N).
// LDS per buffer (64KB): Ah0@0, Ah1@16K, G@32K, U@48K (each 128 rows x 128B).
// Register-reuse phase order (24 ds_read_b128 / K-tile / wave):
//   ph0: read A-mh0 + WG  -> g.mh0      ph1: read A-mh1 -> g.mh1 (WG held)
//   ph2: read WU          -> u.mh0      ph3: (all held) -> u.mh1
// ===========================================================================
__global__ __launch_bounds__(512, 2) void gateup8_kernel(
    const __bf16* __restrict__ X, const __bf16* __restrict__ Gw,
    const __bf16* __restrict__ Uw, __bf16* __restrict__ act)
{
  extern __shared__ char smem[];   // 2 x 64KB
  const int tid  = threadIdx.x;
  const int lane = tid & 63;
  const int wave = tid >> 6;
  const int wm = wave >> 1, wn = wave & 1;
  const int e  = blockIdx.z;
  const int m0 = e * CHUNK + blockIdx.y * 256;   // row into X/act
  const int n0 = e * IDIM  + blockIdx.x * 128;   // row into Gw/Uw

  int su[2], skk[2];
#pragma unroll
  for (int j = 0; j < 2; ++j) {
    int P = j * 8192 + tid * 16;
    int L = P ^ (((P >> 7) & 7) << 4);   // same 3-bit involution as RDF
    su[j]  = L >> 7;
    skk[j] = (L & 127) >> 1;
  }
  const int ldsw = wave * 1024;

  auto stageA = [&](char* bb, int h, int kt2) {
#pragma unroll
    for (int j = 0; j < 2; ++j) {
      int u = su[j];
      int r = (u & 31) + h * 32 + (u >> 5) * 64;
      const __bf16* src = X + (size_t)(m0 + r) * HDIM + kt2 * 64 + skk[j];
      GLDS16(src, bb + h * 16384 + j * 8192 + ldsw);
    }
  };
  auto stageW = [&](char* bb, int w, int kt2) {   // w: 0=G, 1=U
    const __bf16* W = w ? Uw : Gw;
#pragma unroll
    for (int j = 0; j < 2; ++j) {
      const __bf16* src = W + (size_t)(n0 + su[j]) * HDIM + kt2 * 64 + skk[j];
      GLDS16(src, bb + 32768 + w * 16384 + j * 8192 + ldsw);
    }
  };

  f32x4 accg[4][4], accu[4][4];
#pragma unroll
  for (int m = 0; m < 4; ++m)
#pragma unroll
    for (int n = 0; n < 4; ++n)
#pragma unroll
      for (int j = 0; j < 4; ++j) { accg[m][n][j] = 0.f; accu[m][n][j] = 0.f; }

  const int frow = lane & 15;
  const int q16  = (lane >> 4) * 16;
  const int NT   = HDIM / 64;   // 32

  {
    char* s0 = smem;
    char* s1 = smem + 65536;
    stageA(s0, 0, 0); stageW(s0, 0, 0); stageA(s0, 1, 0); stageW(s0, 1, 0);
    stageA(s1, 0, 1); stageW(s1, 0, 1);
  }
  WAITV(4); BAR();

  for (int kt = 0; kt < NT; ++kt) {
    const int b = kt & 1;
    char* sb = smem + b * 65536;
    char* so = smem + (b ^ 1) * 65536;
    bf16x8 aF0[2][2], aF1[2][2], wF[4][2];

    // ---- phase 0: read A-mh0 + WG; g.mh0 ----
#pragma unroll
    for (int m = 0; m < 2; ++m) { int rp = wm * 32 + m * 16 + frow;
      aF0[m][0] = RDF(sb, rp, 0); aF0[m][1] = RDF(sb, rp, 1); }
#pragma unroll
    for (int n = 0; n < 4; ++n) { int rp = wn * 64 + n * 16 + frow;
      wF[n][0] = RDF(sb + 32768, rp, 0); wF[n][1] = RDF(sb + 32768, rp, 1); }
    if (kt + 1 < NT) stageA(so, 1, kt + 1);
    BAR();
    __builtin_amdgcn_s_setprio(1);
#pragma unroll
    for (int n = 0; n < 4; ++n)
#pragma unroll
      for (int m = 0; m < 2; ++m) {
        accg[m][n] = MFMA(aF0[m][0], wF[n][0], accg[m][n]);
        accg[m][n] = MFMA(aF0[m][1], wF[n][1], accg[m][n]);
      }
    __builtin_amdgcn_s_setprio(0);
    BAR();

    // ---- phase 1: read A-mh1; g.mh1 (WG held) ----
#pragma unroll
    for (int m = 0; m < 2; ++m) { int rp = wm * 32 + m * 16 + frow;
      aF1[m][0] = RDF(sb + 16384, rp, 0); aF1[m][1] = RDF(sb + 16384, rp, 1); }
    if (kt + 1 < NT) stageW(so, 1, kt + 1);
    BAR();
    __builtin_amdgcn_s_setprio(1);
#pragma unroll
    for (int n = 0; n < 4; ++n)
#pragma unroll
      for (int m = 0; m < 2; ++m) {
        accg[2 + m][n] = MFMA(aF1[m][0], wF[n][0], accg[2 + m][n]);
        accg[2 + m][n] = MFMA(aF1[m][1], wF[n][1], accg[2 + m][n]);
      }
    __builtin_amdgcn_s_setprio(0);
    BAR();

    // ---- phase 2: read WU; u.mh0 (A-mh0 held) ----
#pragma unroll
    for (int n = 0; n < 4; ++n) { int rp = wn * 64 + n * 16 + frow;
      wF[n][0] = RDF(sb + 49152, rp, 0); wF[n][1] = RDF(sb + 49152, rp, 1); }
    if (kt + 2 < NT) stageA(sb, 0, kt + 2);
    BAR();
    __builtin_amdgcn_s_setprio(1);
#pragma unroll
    for (int n = 0; n < 4; ++n)
#pragma unroll
      for (int m = 0; m < 2; ++m) {
        accu[m][n] = MFMA(aF0[m][0], wF[n][0], accu[m][n]);
        accu[m][n] = MFMA(aF0[m][1], wF[n][1], accu[m][n]);
      }
    __builtin_amdgcn_s_setprio(0);
    BAR();

    // ---- phase 3: u.mh1 (all held) ----
    if (kt + 2 < NT) stageW(sb, 0, kt + 2);
    BAR();
    __builtin_amdgcn_s_setprio(1);
#pragma unroll
    for (int n = 0; n < 4; ++n)
#pragma unroll
      for (int m = 0; m < 2; ++m) {
        accu[2 + m][n] = MFMA(aF1[m][0], wF[n][0], accu[2 + m][n]);
        accu[2 + m][n] = MFMA(aF1[m][1], wF[n][1], accu[2 + m][n]);
      }
    __builtin_amdgcn_s_setprio(0);
    if (kt < NT - 2) { WAITV(4); } else if (kt == NT - 2) { WAITV(0); }
    BAR();
  }

  // epilogue: silu(g)*u -> bf16 act
  const int orow0 = m0 + wm * 64 + (lane >> 4) * 4;
  const int ocol0 = blockIdx.x * 128 + wn * 64 + frow;
#pragma unroll
  for (int m = 0; m < 4; ++m)
#pragma unroll
    for (int n = 0; n < 4; ++n)
#pragma unroll
      for (int j = 0; j < 4; ++j) {
        float g = accg[m][n][j];
        float u = accu[m][n][j];
        float s = g / (1.0f + __expf(-g));
        act[(size_t)(orow0 + m * 16 + j) * IDIM + (ocol0 + n * 16)] = (__bf16)(s * u);
      }
}

// ===========================================================================
// 8-phase down GEMM: out = act . Dw^T (f32 out). BM=BN=256, BK=64.
// 8 waves (2M x 4N); per-wave 128x64; acc[8][4].
// Register-reuse phase order (24 ds_read_b128 / K-tile / wave):
//   ph0: read A-mh0 + B-nh0 -> (mh0,nh0)   ph1: read B-nh1 -> (mh0,nh1)
//   ph2: read A-mh1 -> (mh1,nh0; B-nh0 held)  ph3: (held) -> (mh1,nh1)
// ===========================================================================
__global__ __launch_bounds__(512, 2) void down8_kernel(
    const __bf16* __restrict__ act, const __bf16* __restrict__ Dw,
    float* __restrict__ out)
{
  extern __shared__ char smem[];
  const int tid  = threadIdx.x;
  const int lane = tid & 63;
  const int wave = tid >> 6;
  const int wr = wave >> 2, wc = wave & 3;
  const int e  = blockIdx.z;
  const int m0 = e * CHUNK + blockIdx.y * 256;
  const int n0 = e * HDIM  + blockIdx.x * 256;

  int su[2], skk[2];
#pragma unroll
  for (int j = 0; j < 2; ++j) {
    int P = j * 8192 + tid * 16;
    int L = P ^ (((P >> 7) & 7) << 4);
    su[j]  = L >> 7;
    skk[j] = (L & 127) >> 1;
  }
  const int ldsw = wave * 1024;

  auto stageA = [&](char* bb, int h, int kt2) {
#pragma unroll
    for (int j = 0; j < 2; ++j) {
      int u = su[j];
      int r = (u & 63) + h * 64 + (u >> 6) * 128;
      const __bf16* src = act + (size_t)(m0 + r) * IDIM + kt2 * 64 + skk[j];
      GLDS16(src, bb + h * 16384 + j * 8192 + ldsw);
    }
  };
  auto stageB = [&](char* bb, int h, int kt2) {
#pragma unroll
    for (int j = 0; j < 2; ++j) {
      int u = su[j];
      int r = (u & 31) + h * 32 + (u >> 5) * 64;
      const __bf16* src = Dw + (size_t)(n0 + r) * IDIM + kt2 * 64 + skk[j];
      GLDS16(src, bb + 32768 + h * 16384 + j * 8192 + ldsw);
    }
  };

  f32x4 acc[8][4];
#pragma unroll
  for (int m = 0; m < 8; ++m)
#pragma unroll
    for (int n = 0; n < 4; ++n)
#pragma unroll
      for (int j = 0; j < 4; ++j) acc[m][n][j] = 0.f;

  const int frow = lane & 15;
  const int q16  = (lane >> 4) * 16;
  const int NT   = IDIM / 64;   // 128

  {
    char* s0 = smem;
    char* s1 = smem + 65536;
    stageA(s0, 0, 0); stageB(s0, 0, 0); stageA(s0, 1, 0); stageB(s0, 1, 0);
    stageA(s1, 0, 1); stageB(s1, 0, 1);
  }
  WAITV(4); BAR();

  for (int kt = 0; kt < NT; ++kt) {
    const int b = kt & 1;
    char* sb = smem + b * 65536;
    char* so = smem + (b ^ 1) * 65536;
    bf16x8 aF[4][2], bF0[2][2], bF1[2][2];

    // ---- phase 0: read A-mh0 + B-nh0; (mh0,nh0) ----
#pragma unroll
    for (int m = 0; m < 4; ++m) { int rp = wr * 64 + m * 16 + frow;
      aF[m][0] = RDF(sb, rp, 0); aF[m][1] = RDF(sb, rp, 1); }
#pragma unroll
    for (int n = 0; n < 2; ++n) { int rp = wc * 32 + n * 16 + frow;
      bF0[n][0] = RDF(sb + 32768, rp, 0); bF0[n][1] = RDF(sb + 32768, rp, 1); }
    if (kt + 1 < NT) stageA(so, 1, kt + 1);
    BAR();
    __builtin_amdgcn_s_setprio(1);
#pragma unroll
    for (int n = 0; n < 2; ++n)
#pragma unroll
      for (int m = 0; m < 4; ++m) {
        acc[m][n] = MFMA(aF[m][0], bF0[n][0], acc[m][n]);
        acc[m][n] = MFMA(aF[m][1], bF0[n][1], acc[m][n]);
      }
    __builtin_amdgcn_s_setprio(0);
    BAR();

    // ---- phase 1: read B-nh1; (mh0,nh1) ----
#pragma unroll
    for (int n = 0; n < 2; ++n) { int rp = wc * 32 + n * 16 + frow;
      bF1[n][0] = RDF(sb + 49152, rp, 0); bF1[n][1] = RDF(sb + 49152, rp, 1); }
    if (kt + 1 < NT) stageB(so, 1, kt + 1);
    BAR();
    __builtin_amdgcn_s_setprio(1);
#pragma unroll
    for (int n = 0; n < 2; ++n)
#pragma unroll
      for (int m = 0; m < 4; ++m) {
        acc[m][2 + n] = MFMA(aF[m][0], bF1[n][0], acc[m][2 + n]);
        acc[m][2 + n] = MFMA(aF[m][1], bF1[n][1], acc[m][2 + n]);
      }
    __builtin_amdgcn_s_setprio(0);
    BAR();

    // ---- phase 2: read A-mh1; (mh1,nh0) (B-nh0 held) ----
#pragma unroll
    for (int m = 0; m < 4; ++m) { int rp = wr * 64 + m * 16 + frow;
      aF[m][0] = RDF(sb + 16384, rp, 0); aF[m][1] = RDF(sb + 16384, rp, 1); }
    if (kt + 2 < NT) stageA(sb, 0, kt + 2);
    BAR();
    __builtin_amdgcn_s_setprio(1);
#pragma unroll
    for (int n = 0; n < 2; ++n)
#pragma unroll
      for (int m = 0; m < 4; ++m) {
        acc[4 + m][n] = MFMA(aF[m][0], bF0[n][0], acc[4 + m][n]);
        acc[4 + m][n] = MFMA(aF[m][1], bF0[n][1], acc[4 + m][n]);
      }
    __builtin_amdgcn_s_setprio(0);
    BAR();

    // ---- phase 3: (mh1,nh1) (all held) ----
    if (kt + 2 < NT) stageB(sb, 0, kt + 2);
    BAR();
    __builtin_amdgcn_s_setprio(1);
#pragma unroll
    for (int n = 0; n < 2; ++n)
#pragma unroll
      for (int m = 0; m < 4; ++m) {
        acc[4 + m][2 + n] = MFMA(aF[m][0], bF1[n][0], acc[4 + m][2 + n]);
        acc[4 + m][2 + n] = MFMA(aF[m][1], bF1[n][1], acc[4 + m][2 + n]);
      }
    __builtin_amdgcn_s_setprio(0);
    if (kt < NT - 2) { WAITV(4); } else if (kt == NT - 2) { WAITV(0); }
    BAR();
  }

  const int orow0 = m0 + wr * 128 + (lane >> 4) * 4;
  const int ocol0 = blockIdx.x * 256 + wc * 64 + frow;
#pragma unroll
  for (int m = 0; m < 8; ++m)
#pragma unroll
    for (int n = 0; n < 4; ++n)
#pragma unroll
      for (int j = 0; j < 4; ++j)
        out[(size_t)(orow0 + m * 16 + j) * HDIM + (ocol0 + n * 16)] = acc[m][n][j];
}

// ===========================================================================
// Fallback: round-3 kernels (128^2 2-barrier, per-expert) if ws is small.
// ===========================================================================
__global__ __launch_bounds__(256) void gateup2_kernel(
    const __bf16* __restrict__ X, const __bf16* __restrict__ Gw,
    const __bf16* __restrict__ Uw, __bf16* __restrict__ act)
{
  __shared__ __bf16 lds[2][3][128 * 32];
  const int tid  = threadIdx.x;
  const int lane = tid & 63;
  const int wave = tid >> 6;
  const int wr = wave >> 1, wc = wave & 1;
  const int m0 = blockIdx.x * 128;
  const int n0 = blockIdx.y * 128;

  int srow[2], scol[2];
#pragma unroll
  for (int h = 0; h < 2; ++h) {
    const int B  = h * 4096 + tid * 16;
    const int Bs = B ^ (((B >> 7) & 3) << 4);
    srow[h] = Bs >> 6;
    scol[h] = (Bs & 63) >> 1;
  }
  const int ldst_off[2] = { wave * 1024, 4096 + wave * 1024 };

  f32x4 accg[4][4], accu[4][4];
#pragma unroll
  for (int m = 0; m < 4; ++m)
#pragma unroll
    for (int n = 0; n < 4; ++n)
#pragma unroll
      for (int j = 0; j < 4; ++j) { accg[m][n][j] = 0.f; accu[m][n][j] = 0.f; }

  const int frow  = lane & 15;
  const int rdoff = ((lane >> 4) * 16) ^ (((frow >> 1) & 3) << 4);

  auto stage = [&](int buf, int kt) {
    const int k0 = kt * 32;
#pragma unroll
    for (int h = 0; h < 2; ++h) {
      GLDS16(X  + (size_t)(m0 + srow[h]) * HDIM + k0 + scol[h], (char*)&lds[buf][0][0] + ldst_off[h]);
      GLDS16(Gw + (size_t)(n0 + srow[h]) * HDIM + k0 + scol[h], (char*)&lds[buf][1][0] + ldst_off[h]);
      GLDS16(Uw + (size_t)(n0 + srow[h]) * HDIM + k0 + scol[h], (char*)&lds[buf][2][0] + ldst_off[h]);
    }
  };

  const int NT = HDIM / 32;
  stage(0, 0);
  int cur = 0;
  for (int kt = 0; kt < NT; ++kt) {
    __syncthreads();
    if (kt + 1 < NT) stage(cur ^ 1, kt + 1);
    const char* bA = (const char*)&lds[cur][0][0];
    const char* bG = (const char*)&lds[cur][1][0];
    const char* bU = (const char*)&lds[cur][2][0];
    bf16x8 af[4];
#pragma unroll
    for (int m = 0; m < 4; ++m)
      af[m] = *(const bf16x8*)(bA + (wr * 64 + m * 16 + frow) * 64 + rdoff);
#pragma unroll
    for (int n = 0; n < 4; ++n) {
      bf16x8 bg = *(const bf16x8*)(bG + (wc * 64 + n * 16 + frow) * 64 + rdoff);
      bf16x8 bu = *(const bf16x8*)(bU + (wc * 64 + n * 16 + frow) * 64 + rdoff);
#pragma unroll
      for (int m = 0; m < 4; ++m) {
        accg[m][n] = MFMA(af[m], bg, accg[m][n]);
        accu[m][n] = MFMA(af[m], bu, accu[m][n]);
      }
    }
    cur ^= 1;
  }
  const int orow = m0 + wr * 64 + (lane >> 4) * 4;
  const int ocol = n0 + wc * 64 + (lane & 15);
#pragma unroll
  for (int m = 0; m < 4; ++m)
#pragma unroll
    for (int n = 0; n < 4; ++n)
#pragma unroll
      for (int j = 0; j < 4; ++j) {
        float g = accg[m][n][j];
        float u = accu[m][n][j];
        float s = g / (1.0f + __expf(-g));
        act[(size_t)(orow + m * 16 + j) * IDIM + (ocol + n * 16)] = (__bf16)(s * u);
      }
}

__global__ __launch_bounds__(256) void down2_kernel(
    const __bf16* __restrict__ act, const __bf16* __restrict__ Dw,
    float* __restrict__ out)
{
  __shared__ __bf16 lds[2][2][128 * 32];
  const int tid  = threadIdx.x;
  const int lane = tid & 63;
  const int wave = tid >> 6;
  const int wr = wave >> 1, wc = wave & 1;
  const int m0 = blockIdx.x * 128;
  const int n0 = blockIdx.y * 128;

  int srow[2], scol[2];
#pragma unroll
  for (int h = 0; h < 2; ++h) {
    const int B  = h * 4096 + tid * 16;
    const int Bs = B ^ (((B >> 7) & 3) << 4);
    srow[h] = Bs >> 6;
    scol[h] = (Bs & 63) >> 1;
  }
  const int ldst_off[2] = { wave * 1024, 4096 + wave * 1024 };

  f32x4 acc[4][4];
#pragma unroll
  for (int m = 0; m < 4; ++m)
#pragma unroll
    for (int n = 0; n < 4; ++n)
#pragma unroll
      for (int j = 0; j < 4; ++j) acc[m][n][j] = 0.f;

  const int frow  = lane & 15;
  const int rdoff = ((lane >> 4) * 16) ^ (((frow >> 1) & 3) << 4);

  auto stage = [&](int buf, int kt) {
    const int k0 = kt * 32;
#pragma unroll
    for (int h = 0; h < 2; ++h) {
      GLDS16(act + (size_t)(m0 + srow[h]) * IDIM + k0 + scol[h], (char*)&lds[buf][0][0] + ldst_off[h]);
      GLDS16(Dw  + (size_t)(n0 + srow[h]) * IDIM + k0 + scol[h], (char*)&lds[buf][1][0] + ldst_off[h]);
    }
  };

  const int NT = IDIM / 32;
  stage(0, 0);
  int cur = 0;
  for (int kt = 0; kt < NT; ++kt) {
    __syncthreads();
    if (kt + 1 < NT) stage(cur ^ 1, kt + 1);
    const char* bA = (const char*)&lds[cur][0][0];
    const char* bW = (const char*)&lds[cur][1][0];
    bf16x8 af[4];
#pragma unroll
    for (int m = 0; m < 4; ++m)
      af[m] = *(const bf16x8*)(bA + (wr * 64 + m * 16 + frow) * 64 + rdoff);
#pragma unroll
    for (int n = 0; n < 4; ++n) {
      bf16x8 bw = *(const bf16x8*)(bW + (wc * 64 + n * 16 + frow) * 64 + rdoff);
#pragma unroll
      for (int m = 0; m < 4; ++m)
        acc[m][n] = MFMA(af[m], bw, acc[m][n]);
    }
    cur ^= 1;
  }
  const int orow = m0 + wr * 64 + (lane >> 4) * 4;
  const int ocol = n0 + wc * 64 + (lane & 15);
#pragma unroll
  for (int m = 0; m < 4; ++m)
#pragma unroll
    for (int n = 0; n < 4; ++n)
#pragma unroll
      for (int j = 0; j < 4; ++j)
        out[(size_t)(orow + m * 16 + j) * HDIM + (ocol + n * 16)] = acc[m][n][j];
}

// ---------------------------------------------------------------------------
extern "C" void kernel_launch(void* const* d_in, const int* in_sizes, int n_in,
                              void* d_out, int out_size, void* d_ws, size_t ws_size,
                              hipStream_t stream)
{
  const float* hidden = (const float*)d_in[0];
  const float* gate_w = (const float*)d_in[1];
  const float* up_w   = (const float*)d_in[2];
  const float* down_w = (const float*)d_in[3];
  float* out = (float*)d_out;

  const size_t SZ_X    = (size_t)32768 * HDIM;
  const size_t SZ_Wall = (size_t)E_NUM * IDIM * HDIM;
  const size_t SZ_ACT  = (size_t)32768 * IDIM;
  const size_t need8 = (SZ_X + 3 * SZ_Wall + SZ_ACT) * sizeof(__bf16);  // ~1.48 GB

  if (ws_size >= need8) {
    __bf16* xb  = (__bf16*)d_ws;
    __bf16* gwb = xb  + SZ_X;
    __bf16* uwb = gwb + SZ_Wall;
    __bf16* dwb = uwb + SZ_Wall;
    __bf16* actb = dwb + SZ_Wall;

    cvt_kernel<<<SZ_X    / 2048, 256, 0, stream>>>(hidden, xb);
    cvt_kernel<<<SZ_Wall / 2048, 256, 0, stream>>>(gate_w, gwb);
    cvt_kernel<<<SZ_Wall / 2048, 256, 0, stream>>>(up_w,   uwb);
    cvt_kernel<<<SZ_Wall / 2048, 256, 0, stream>>>(down_w, dwb);

    gateup8_kernel<<<dim3(IDIM / 128, CHUNK / 256, E_NUM), 512, 131072, stream>>>(xb, gwb, uwb, actb);
    down8_kernel  <<<dim3(HDIM / 256, CHUNK / 256, E_NUM), 512, 131072, stream>>>(actb, dwb, out);
  } else {
    const size_t sX = (size_t)CHUNK * HDIM;
    const size_t sW = (size_t)IDIM * HDIM;
    __bf16* xb = (__bf16*)d_ws;
    __bf16* gb = xb + sX;
    __bf16* ub = gb + sW;
    __bf16* db = ub + sW;
    __bf16* act = db + sW;
    for (int e = 0; e < E_NUM; ++e) {
      const float* Xe = hidden + (size_t)e * sX;
      const float* Ge = gate_w + (size_t)e * sW;
      const float* Ue = up_w   + (size_t)e * sW;
      const float* De = down_w + (size_t)e * sW;
      float* Oe = out + (size_t)e * CHUNK * HDIM;
      cvt_kernel<<<sX / 2048, 256, 0, stream>>>(Xe, xb);
      cvt_kernel<<<sW / 2048, 256, 0, stream>>>(Ge, gb);
      cvt_kernel<<<sW / 2048, 256, 0, stream>>>(Ue, ub);
      cvt_kernel<<<sW / 2048, 256, 0, stream>>>(De, db);
      gateup2_kernel<<<dim3(CHUNK / 128, IDIM / 128), 256, 0, stream>>>(xb, gb, ub, act);
      down2_kernel<<<dim3(CHUNK / 128, HDIM / 128), 256, 0, stream>>>(act, db, Oe);
    }
  }
}

// Round 7
// 3175.992 us; speedup vs baseline: 2.9352x; 1.0208x over previous
//
#include <hip/hip_runtime.h>
#include <hip/hip_bf16.h>
#include <stdint.h>

// Problem constants (fixed by setup_inputs)
#define E_NUM 8
#define CHUNK 4096
#define HDIM  2048
#define IDIM  8192

typedef __bf16 bf16x8 __attribute__((ext_vector_type(8)));
typedef __bf16 bf16x4 __attribute__((ext_vector_type(4)));
typedef float  f32x4  __attribute__((ext_vector_type(4)));

#define GLDS16(g, l) __builtin_amdgcn_global_load_lds(                         \
    (const __attribute__((address_space(1))) void*)(g),                        \
    (__attribute__((address_space(3))) void*)(l), 16, 0, 0)
#define MFMA(a, b, c) __builtin_amdgcn_mfma_f32_16x16x32_bf16((a), (b), (c), 0, 0, 0)
#define FENCE() asm volatile("" ::: "memory")
#define BAR()   do { FENCE(); __builtin_amdgcn_s_barrier(); FENCE(); } while (0)
#define WAITV(n) asm volatile("s_waitcnt vmcnt(" #n ")" ::: "memory")

// frag read from a 128-row x 128B LDS region; 3-bit XOR swizzle:
// 8 slots/row (bits 4-6) XOR row bits 0-2 -> 16-lane row-sweep = conflict-free
#define RDF(base, rp, ks) \
  (*(const bf16x8*)((base) + (rp) * 128 + ((((ks) * 64) + q16) ^ (((rp) & 7) << 4))))

// ---------------------------------------------------------------------------
// f32 -> bf16 conversion (memory-bound, 8 elems/thread)
// ---------------------------------------------------------------------------
__global__ __launch_bounds__(256) void cvt_kernel(
    const float* __restrict__ src, __bf16* __restrict__ dst)
{
  const size_t i = ((size_t)blockIdx.x * 256 + threadIdx.x) * 8;
  float4 a = *reinterpret_cast<const float4*>(src + i);
  float4 b = *reinterpret_cast<const float4*>(src + i + 4);
  bf16x8 r;
  r[0] = (__bf16)a.x; r[1] = (__bf16)a.y; r[2] = (__bf16)a.z; r[3] = (__bf16)a.w;
  r[4] = (__bf16)b.x; r[5] = (__bf16)b.y; r[6] = (__bf16)b.z; r[7] = (__bf16)b.w;
  *reinterpret_cast<bf16x8*>(dst + i) = r;
}

// ===========================================================================
// Fused gate+up GEMM.  BM=256 x BN=128, BK=64. 8 waves (4M x 2N).
// LDS per buffer (64KB): Ah0@0, Ah1@16K, G@32K, U@48K (each 128 rows x 128B).
// ONE barrier per phase (phase-end). Stage issued FIRST in each phase.
// Correctness: each region is re-staged >=2 phase-end barriers after its
// last read (ph0 reads Ah0+G; ph1 reads Ah1; ph2 reads U; stages:
// ph0->so.Ah1, ph1->so.U, ph2->sb.Ah0[kt+2], ph3->sb.G[kt+2]).
// ===========================================================================
__global__ __launch_bounds__(512, 2) void gateup8_kernel(
    const __bf16* __restrict__ X, const __bf16* __restrict__ Gw,
    const __bf16* __restrict__ Uw, __bf16* __restrict__ act)
{
  extern __shared__ char smem[];   // 2 x 64KB
  const int tid  = threadIdx.x;
  const int lane = tid & 63;
  const int wave = tid >> 6;
  const int wm = wave >> 1, wn = wave & 1;
  const int e  = blockIdx.z;
  const int m0 = e * CHUNK + blockIdx.y * 256;   // row into X/act
  const int n0 = e * IDIM  + blockIdx.x * 128;   // row into Gw/Uw

  int su[2], skk[2];
#pragma unroll
  for (int j = 0; j < 2; ++j) {
    int P = j * 8192 + tid * 16;
    int L = P ^ (((P >> 7) & 7) << 4);   // same 3-bit involution as RDF
    su[j]  = L >> 7;
    skk[j] = (L & 127) >> 1;
  }
  const int ldsw = wave * 1024;

  auto stageA = [&](char* bb, int h, int kt2) {
#pragma unroll
    for (int j = 0; j < 2; ++j) {
      int u = su[j];
      int r = (u & 31) + h * 32 + (u >> 5) * 64;
      const __bf16* src = X + (size_t)(m0 + r) * HDIM + kt2 * 64 + skk[j];
      GLDS16(src, bb + h * 16384 + j * 8192 + ldsw);
    }
  };
  auto stageW = [&](char* bb, int w, int kt2) {   // w: 0=G, 1=U
    const __bf16* W = w ? Uw : Gw;
#pragma unroll
    for (int j = 0; j < 2; ++j) {
      const __bf16* src = W + (size_t)(n0 + su[j]) * HDIM + kt2 * 64 + skk[j];
      GLDS16(src, bb + 32768 + w * 16384 + j * 8192 + ldsw);
    }
  };

  f32x4 accg[4][4], accu[4][4];
#pragma unroll
  for (int m = 0; m < 4; ++m)
#pragma unroll
    for (int n = 0; n < 4; ++n)
#pragma unroll
      for (int j = 0; j < 4; ++j) { accg[m][n][j] = 0.f; accu[m][n][j] = 0.f; }

  const int frow = lane & 15;
  const int q16  = (lane >> 4) * 16;
  const int NT   = HDIM / 64;   // 32

  {
    char* s0 = smem;
    char* s1 = smem + 65536;
    stageA(s0, 0, 0); stageW(s0, 0, 0); stageA(s0, 1, 0); stageW(s0, 1, 0);
    stageA(s1, 0, 1); stageW(s1, 0, 1);
  }
  WAITV(4); BAR();

  for (int kt = 0; kt < NT; ++kt) {
    const int b = kt & 1;
    char* sb = smem + b * 65536;
    char* so = smem + (b ^ 1) * 65536;
    bf16x8 aF0[2][2], aF1[2][2], wF[4][2];

    // ---- phase 0: stage so.Ah1 | read A-mh0 + WG | g.mh0 ----
    if (kt + 1 < NT) stageA(so, 1, kt + 1);
#pragma unroll
    for (int m = 0; m < 2; ++m) { int rp = wm * 32 + m * 16 + frow;
      aF0[m][0] = RDF(sb, rp, 0); aF0[m][1] = RDF(sb, rp, 1); }
#pragma unroll
    for (int n = 0; n < 4; ++n) { int rp = wn * 64 + n * 16 + frow;
      wF[n][0] = RDF(sb + 32768, rp, 0); wF[n][1] = RDF(sb + 32768, rp, 1); }
    __builtin_amdgcn_s_setprio(1);
#pragma unroll
    for (int n = 0; n < 4; ++n)
#pragma unroll
      for (int m = 0; m < 2; ++m) {
        accg[m][n] = MFMA(aF0[m][0], wF[n][0], accg[m][n]);
        accg[m][n] = MFMA(aF0[m][1], wF[n][1], accg[m][n]);
      }
    __builtin_amdgcn_s_setprio(0);
    BAR();

    // ---- phase 1: stage so.U | read A-mh1 | g.mh1 (WG held) ----
    if (kt + 1 < NT) stageW(so, 1, kt + 1);
#pragma unroll
    for (int m = 0; m < 2; ++m) { int rp = wm * 32 + m * 16 + frow;
      aF1[m][0] = RDF(sb + 16384, rp, 0); aF1[m][1] = RDF(sb + 16384, rp, 1); }
    __builtin_amdgcn_s_setprio(1);
#pragma unroll
    for (int n = 0; n < 4; ++n)
#pragma unroll
      for (int m = 0; m < 2; ++m) {
        accg[2 + m][n] = MFMA(aF1[m][0], wF[n][0], accg[2 + m][n]);
        accg[2 + m][n] = MFMA(aF1[m][1], wF[n][1], accg[2 + m][n]);
      }
    __builtin_amdgcn_s_setprio(0);
    BAR();

    // ---- phase 2: stage sb.Ah0[kt+2] | read WU | u.mh0 (A-mh0 held) ----
    if (kt + 2 < NT) stageA(sb, 0, kt + 2);
#pragma unroll
    for (int n = 0; n < 4; ++n) { int rp = wn * 64 + n * 16 + frow;
      wF[n][0] = RDF(sb + 49152, rp, 0); wF[n][1] = RDF(sb + 49152, rp, 1); }
    __builtin_amdgcn_s_setprio(1);
#pragma unroll
    for (int n = 0; n < 4; ++n)
#pragma unroll
      for (int m = 0; m < 2; ++m) {
        accu[m][n] = MFMA(aF0[m][0], wF[n][0], accu[m][n]);
        accu[m][n] = MFMA(aF0[m][1], wF[n][1], accu[m][n]);
      }
    __builtin_amdgcn_s_setprio(0);
    BAR();

    // ---- phase 3: stage sb.G[kt+2] | u.mh1 (all held) ----
    if (kt + 2 < NT) stageW(sb, 0, kt + 2);
    __builtin_amdgcn_s_setprio(1);
#pragma unroll
    for (int n = 0; n < 4; ++n)
#pragma unroll
      for (int m = 0; m < 2; ++m) {
        accu[2 + m][n] = MFMA(aF1[m][0], wF[n][0], accu[2 + m][n]);
        accu[2 + m][n] = MFMA(aF1[m][1], wF[n][1], accu[2 + m][n]);
      }
    __builtin_amdgcn_s_setprio(0);
    if (kt < NT - 2) { WAITV(4); } else if (kt == NT - 2) { WAITV(0); }
    BAR();
  }

  // epilogue: silu(g)*u -> bf16 act
  const int orow0 = m0 + wm * 64 + (lane >> 4) * 4;
  const int ocol0 = blockIdx.x * 128 + wn * 64 + frow;
#pragma unroll
  for (int m = 0; m < 4; ++m)
#pragma unroll
    for (int n = 0; n < 4; ++n)
#pragma unroll
      for (int j = 0; j < 4; ++j) {
        float g = accg[m][n][j];
        float u = accu[m][n][j];
        float s = g / (1.0f + __expf(-g));
        act[(size_t)(orow0 + m * 16 + j) * IDIM + (ocol0 + n * 16)] = (__bf16)(s * u);
      }
}

// ===========================================================================
// Down GEMM: out = act . Dw^T (f32 out). BM=BN=256, BK=64.
// 8 waves (2M x 4N); per-wave 128x64; acc[8][4]. Single barrier per phase.
// ph0 reads A-mh0+B-nh0; ph1 reads B-nh1; ph2 reads A-mh1; ph3 none.
// Stages: ph0->so.Ah1, ph1->so.B1, ph2->sb.Ah0[kt+2], ph3->sb.B0[kt+2].
// ===========================================================================
__global__ __launch_bounds__(512, 2) void down8_kernel(
    const __bf16* __restrict__ act, const __bf16* __restrict__ Dw,
    float* __restrict__ out)
{
  extern __shared__ char smem[];
  const int tid  = threadIdx.x;
  const int lane = tid & 63;
  const int wave = tid >> 6;
  const int wr = wave >> 2, wc = wave & 3;
  const int e  = blockIdx.z;
  const int m0 = e * CHUNK + blockIdx.y * 256;
  const int n0 = e * HDIM  + blockIdx.x * 256;

  int su[2], skk[2];
#pragma unroll
  for (int j = 0; j < 2; ++j) {
    int P = j * 8192 + tid * 16;
    int L = P ^ (((P >> 7) & 7) << 4);
    su[j]  = L >> 7;
    skk[j] = (L & 127) >> 1;
  }
  const int ldsw = wave * 1024;

  auto stageA = [&](char* bb, int h, int kt2) {
#pragma unroll
    for (int j = 0; j < 2; ++j) {
      int u = su[j];
      int r = (u & 63) + h * 64 + (u >> 6) * 128;
      const __bf16* src = act + (size_t)(m0 + r) * IDIM + kt2 * 64 + skk[j];
      GLDS16(src, bb + h * 16384 + j * 8192 + ldsw);
    }
  };
  auto stageB = [&](char* bb, int h, int kt2) {
#pragma unroll
    for (int j = 0; j < 2; ++j) {
      int u = su[j];
      int r = (u & 31) + h * 32 + (u >> 5) * 64;
      const __bf16* src = Dw + (size_t)(n0 + r) * IDIM + kt2 * 64 + skk[j];
      GLDS16(src, bb + 32768 + h * 16384 + j * 8192 + ldsw);
    }
  };

  f32x4 acc[8][4];
#pragma unroll
  for (int m = 0; m < 8; ++m)
#pragma unroll
    for (int n = 0; n < 4; ++n)
#pragma unroll
      for (int j = 0; j < 4; ++j) acc[m][n][j] = 0.f;

  const int frow = lane & 15;
  const int q16  = (lane >> 4) * 16;
  const int NT   = IDIM / 64;   // 128

  {
    char* s0 = smem;
    char* s1 = smem + 65536;
    stageA(s0, 0, 0); stageB(s0, 0, 0); stageA(s0, 1, 0); stageB(s0, 1, 0);
    stageA(s1, 0, 1); stageB(s1, 0, 1);
  }
  WAITV(4); BAR();

  for (int kt = 0; kt < NT; ++kt) {
    const int b = kt & 1;
    char* sb = smem + b * 65536;
    char* so = smem + (b ^ 1) * 65536;
    bf16x8 aF[4][2], bF0[2][2], bF1[2][2];

    // ---- phase 0 ----
    if (kt + 1 < NT) stageA(so, 1, kt + 1);
#pragma unroll
    for (int m = 0; m < 4; ++m) { int rp = wr * 64 + m * 16 + frow;
      aF[m][0] = RDF(sb, rp, 0); aF[m][1] = RDF(sb, rp, 1); }
#pragma unroll
    for (int n = 0; n < 2; ++n) { int rp = wc * 32 + n * 16 + frow;
      bF0[n][0] = RDF(sb + 32768, rp, 0); bF0[n][1] = RDF(sb + 32768, rp, 1); }
    __builtin_amdgcn_s_setprio(1);
#pragma unroll
    for (int n = 0; n < 2; ++n)
#pragma unroll
      for (int m = 0; m < 4; ++m) {
        acc[m][n] = MFMA(aF[m][0], bF0[n][0], acc[m][n]);
        acc[m][n] = MFMA(aF[m][1], bF0[n][1], acc[m][n]);
      }
    __builtin_amdgcn_s_setprio(0);
    BAR();

    // ---- phase 1 ----
    if (kt + 1 < NT) stageB(so, 1, kt + 1);
#pragma unroll
    for (int n = 0; n < 2; ++n) { int rp = wc * 32 + n * 16 + frow;
      bF1[n][0] = RDF(sb + 49152, rp, 0); bF1[n][1] = RDF(sb + 49152, rp, 1); }
    __builtin_amdgcn_s_setprio(1);
#pragma unroll
    for (int n = 0; n < 2; ++n)
#pragma unroll
      for (int m = 0; m < 4; ++m) {
        acc[m][2 + n] = MFMA(aF[m][0], bF1[n][0], acc[m][2 + n]);
        acc[m][2 + n] = MFMA(aF[m][1], bF1[n][1], acc[m][2 + n]);
      }
    __builtin_amdgcn_s_setprio(0);
    BAR();

    // ---- phase 2 ----
    if (kt + 2 < NT) stageA(sb, 0, kt + 2);
#pragma unroll
    for (int m = 0; m < 4; ++m) { int rp = wr * 64 + m * 16 + frow;
      aF[m][0] = RDF(sb + 16384, rp, 0); aF[m][1] = RDF(sb + 16384, rp, 1); }
    __builtin_amdgcn_s_setprio(1);
#pragma unroll
    for (int n = 0; n < 2; ++n)
#pragma unroll
      for (int m = 0; m < 4; ++m) {
        acc[4 + m][n] = MFMA(aF[m][0], bF0[n][0], acc[4 + m][n]);
        acc[4 + m][n] = MFMA(aF[m][1], bF0[n][1], acc[4 + m][n]);
      }
    __builtin_amdgcn_s_setprio(0);
    BAR();

    // ---- phase 3 ----
    if (kt + 2 < NT) stageB(sb, 0, kt + 2);
    __builtin_amdgcn_s_setprio(1);
#pragma unroll
    for (int n = 0; n < 2; ++n)
#pragma unroll
      for (int m = 0; m < 4; ++m) {
        acc[4 + m][2 + n] = MFMA(aF[m][0], bF1[n][0], acc[4 + m][2 + n]);
        acc[4 + m][2 + n] = MFMA(aF[m][1], bF1[n][1], acc[4 + m][2 + n]);
      }
    __builtin_amdgcn_s_setprio(0);
    if (kt < NT - 2) { WAITV(4); } else if (kt == NT - 2) { WAITV(0); }
    BAR();
  }

  const int orow0 = m0 + wr * 128 + (lane >> 4) * 4;
  const int ocol0 = blockIdx.x * 256 + wc * 64 + frow;
#pragma unroll
  for (int m = 0; m < 8; ++m)
#pragma unroll
    for (int n = 0; n < 4; ++n)
#pragma unroll
      for (int j = 0; j < 4; ++j)
        out[(size_t)(orow0 + m * 16 + j) * HDIM + (ocol0 + n * 16)] = acc[m][n][j];
}

// ===========================================================================
// Fallback: round-3 kernels (128^2 2-barrier, per-expert) if ws is small.
// ===========================================================================
__global__ __launch_bounds__(256) void gateup2_kernel(
    const __bf16* __restrict__ X, const __bf16* __restrict__ Gw,
    const __bf16* __restrict__ Uw, __bf16* __restrict__ act)
{
  __shared__ __bf16 lds[2][3][128 * 32];
  const int tid  = threadIdx.x;
  const int lane = tid & 63;
  const int wave = tid >> 6;
  const int wr = wave >> 1, wc = wave & 1;
  const int m0 = blockIdx.x * 128;
  const int n0 = blockIdx.y * 128;

  int srow[2], scol[2];
#pragma unroll
  for (int h = 0; h < 2; ++h) {
    const int B  = h * 4096 + tid * 16;
    const int Bs = B ^ (((B >> 7) & 3) << 4);
    srow[h] = Bs >> 6;
    scol[h] = (Bs & 63) >> 1;
  }
  const int ldst_off[2] = { wave * 1024, 4096 + wave * 1024 };

  f32x4 accg[4][4], accu[4][4];
#pragma unroll
  for (int m = 0; m < 4; ++m)
#pragma unroll
    for (int n = 0; n < 4; ++n)
#pragma unroll
      for (int j = 0; j < 4; ++j) { accg[m][n][j] = 0.f; accu[m][n][j] = 0.f; }

  const int frow  = lane & 15;
  const int rdoff = ((lane >> 4) * 16) ^ (((frow >> 1) & 3) << 4);

  auto stage = [&](int buf, int kt) {
    const int k0 = kt * 32;
#pragma unroll
    for (int h = 0; h < 2; ++h) {
      GLDS16(X  + (size_t)(m0 + srow[h]) * HDIM + k0 + scol[h], (char*)&lds[buf][0][0] + ldst_off[h]);
      GLDS16(Gw + (size_t)(n0 + srow[h]) * HDIM + k0 + scol[h], (char*)&lds[buf][1][0] + ldst_off[h]);
      GLDS16(Uw + (size_t)(n0 + srow[h]) * HDIM + k0 + scol[h], (char*)&lds[buf][2][0] + ldst_off[h]);
    }
  };

  const int NT = HDIM / 32;
  stage(0, 0);
  int cur = 0;
  for (int kt = 0; kt < NT; ++kt) {
    __syncthreads();
    if (kt + 1 < NT) stage(cur ^ 1, kt + 1);
    const char* bA = (const char*)&lds[cur][0][0];
    const char* bG = (const char*)&lds[cur][1][0];
    const char* bU = (const char*)&lds[cur][2][0];
    bf16x8 af[4];
#pragma unroll
    for (int m = 0; m < 4; ++m)
      af[m] = *(const bf16x8*)(bA + (wr * 64 + m * 16 + frow) * 64 + rdoff);
#pragma unroll
    for (int n = 0; n < 4; ++n) {
      bf16x8 bg = *(const bf16x8*)(bG + (wc * 64 + n * 16 + frow) * 64 + rdoff);
      bf16x8 bu = *(const bf16x8*)(bU + (wc * 64 + n * 16 + frow) * 64 + rdoff);
#pragma unroll
      for (int m = 0; m < 4; ++m) {
        accg[m][n] = MFMA(af[m], bg, accg[m][n]);
        accu[m][n] = MFMA(af[m], bu, accu[m][n]);
      }
    }
    cur ^= 1;
  }
  const int orow = m0 + wr * 64 + (lane >> 4) * 4;
  const int ocol = n0 + wc * 64 + (lane & 15);
#pragma unroll
  for (int m = 0; m < 4; ++m)
#pragma unroll
    for (int n = 0; n < 4; ++n)
#pragma unroll
      for (int j = 0; j < 4; ++j) {
        float g = accg[m][n][j];
        float u = accu[m][n][j];
        float s = g / (1.0f + __expf(-g));
        act[(size_t)(orow + m * 16 + j) * IDIM + (ocol + n * 16)] = (__bf16)(s * u);
      }
}

__global__ __launch_bounds__(256) void down2_kernel(
    const __bf16* __restrict__ act, const __bf16* __restrict__ Dw,
    float* __restrict__ out)
{
  __shared__ __bf16 lds[2][2][128 * 32];
  const int tid  = threadIdx.x;
  const int lane = tid & 63;
  const int wave = tid >> 6;
  const int wr = wave >> 1, wc = wave & 1;
  const int m0 = blockIdx.x * 128;
  const int n0 = blockIdx.y * 128;

  int srow[2], scol[2];
#pragma unroll
  for (int h = 0; h < 2; ++h) {
    const int B  = h * 4096 + tid * 16;
    const int Bs = B ^ (((B >> 7) & 3) << 4);
    srow[h] = Bs >> 6;
    scol[h] = (Bs & 63) >> 1;
  }
  const int ldst_off[2] = { wave * 1024, 4096 + wave * 1024 };

  f32x4 acc[4][4];
#pragma unroll
  for (int m = 0; m < 4; ++m)
#pragma unroll
    for (int n = 0; n < 4; ++n)
#pragma unroll
      for (int j = 0; j < 4; ++j) acc[m][n][j] = 0.f;

  const int frow  = lane & 15;
  const int rdoff = ((lane >> 4) * 16) ^ (((frow >> 1) & 3) << 4);

  auto stage = [&](int buf, int kt) {
    const int k0 = kt * 32;
#pragma unroll
    for (int h = 0; h < 2; ++h) {
      GLDS16(act + (size_t)(m0 + srow[h]) * IDIM + k0 + scol[h], (char*)&lds[buf][0][0] + ldst_off[h]);
      GLDS16(Dw  + (size_t)(n0 + srow[h]) * IDIM + k0 + scol[h], (char*)&lds[buf][1][0] + ldst_off[h]);
    }
  };

  const int NT = IDIM / 32;
  stage(0, 0);
  int cur = 0;
  for (int kt = 0; kt < NT; ++kt) {
    __syncthreads();
    if (kt + 1 < NT) stage(cur ^ 1, kt + 1);
    const char* bA = (const char*)&lds[cur][0][0];
    const char* bW = (const char*)&lds[cur][1][0];
    bf16x8 af[4];
#pragma unroll
    for (int m = 0; m < 4; ++m)
      af[m] = *(const bf16x8*)(bA + (wr * 64 + m * 16 + frow) * 64 + rdoff);
#pragma unroll
    for (int n = 0; n < 4; ++n) {
      bf16x8 bw = *(const bf16x8*)(bW + (wc * 64 + n * 16 + frow) * 64 + rdoff);
#pragma unroll
      for (int m = 0; m < 4; ++m)
        acc[m][n] = MFMA(af[m], bw, acc[m][n]);
    }
    cur ^= 1;
  }
  const int orow = m0 + wr * 64 + (lane >> 4) * 4;
  const int ocol = n0 + wc * 64 + (lane & 15);
#pragma unroll
  for (int m = 0; m < 4; ++m)
#pragma unroll
    for (int n = 0; n < 4; ++n)
#pragma unroll
      for (int j = 0; j < 4; ++j)
        out[(size_t)(orow + m * 16 + j) * HDIM + (ocol + n * 16)] = acc[m][n][j];
}

// ---------------------------------------------------------------------------
extern "C" void kernel_launch(void* const* d_in, const int* in_sizes, int n_in,
                              void* d_out, int out_size, void* d_ws, size_t ws_size,
                              hipStream_t stream)
{
  const float* hidden = (const float*)d_in[0];
  const float* gate_w = (const float*)d_in[1];
  const float* up_w   = (const float*)d_in[2];
  const float* down_w = (const float*)d_in[3];
  float* out = (float*)d_out;

  const size_t SZ_X    = (size_t)32768 * HDIM;
  const size_t SZ_Wall = (size_t)E_NUM * IDIM * HDIM;
  const size_t SZ_ACT  = (size_t)32768 * IDIM;
  const size_t need8 = (SZ_X + 3 * SZ_Wall + SZ_ACT) * sizeof(__bf16);  // ~1.48 GB

  if (ws_size >= need8) {
    __bf16* xb  = (__bf16*)d_ws;
    __bf16* gwb = xb  + SZ_X;
    __bf16* uwb = gwb + SZ_Wall;
    __bf16* dwb = uwb + SZ_Wall;
    __bf16* actb = dwb + SZ_Wall;

    cvt_kernel<<<SZ_X    / 2048, 256, 0, stream>>>(hidden, xb);
    cvt_kernel<<<SZ_Wall / 2048, 256, 0, stream>>>(gate_w, gwb);
    cvt_kernel<<<SZ_Wall / 2048, 256, 0, stream>>>(up_w,   uwb);
    cvt_kernel<<<SZ_Wall / 2048, 256, 0, stream>>>(down_w, dwb);

    gateup8_kernel<<<dim3(IDIM / 128, CHUNK / 256, E_NUM), 512, 131072, stream>>>(xb, gwb, uwb, actb);
    down8_kernel  <<<dim3(HDIM / 256, CHUNK / 256, E_NUM), 512, 131072, stream>>>(actb, dwb, out);
  } else {
    const size_t sX = (size_t)CHUNK * HDIM;
    const size_t sW = (size_t)IDIM * HDIM;
    __bf16* xb = (__bf16*)d_ws;
    __bf16* gb = xb + sX;
    __bf16* ub = gb + sW;
    __bf16* db = ub + sW;
    __bf16* act = db + sW;
    for (int e = 0; e < E_NUM; ++e) {
      const float* Xe = hidden + (size_t)e * sX;
      const float* Ge = gate_w + (size_t)e * sW;
      const float* Ue = up_w   + (size_t)e * sW;
      const float* De = down_w + (size_t)e * sW;
      float* Oe = out + (size_t)e * CHUNK * HDIM;
      cvt_kernel<<<sX / 2048, 256, 0, stream>>>(Xe, xb);
      cvt_kernel<<<sW / 2048, 256, 0, stream>>>(Ge, gb);
      cvt_kernel<<<sW / 2048, 256, 0, stream>>>(Ue, ub);
      cvt_kernel<<<sW / 2048, 256, 0, stream>>>(De, db);
      gateup2_kernel<<<dim3(CHUNK / 128, IDIM / 128), 256, 0, stream>>>(xb, gb, ub, act);
      down2_kernel<<<dim3(CHUNK / 128, HDIM / 128), 256, 0, stream>>>(act, db, Oe);
    }
  }
}

// Round 8
// 3140.055 us; speedup vs baseline: 2.9688x; 1.0114x over previous
//
#include <hip/hip_runtime.h>
#include <hip/hip_bf16.h>
#include <stdint.h>

// Problem constants (fixed by setup_inputs)
#define E_NUM 8
#define CHUNK 4096
#define HDIM  2048
#define IDIM  8192

typedef __bf16 bf16x8 __attribute__((ext_vector_type(8)));
typedef __bf16 bf16x4 __attribute__((ext_vector_type(4)));
typedef float  f32x4  __attribute__((ext_vector_type(4)));

#define GLDS16(g, l) __builtin_amdgcn_global_load_lds(                         \
    (const __attribute__((address_space(1))) void*)(g),                        \
    (__attribute__((address_space(3))) void*)(l), 16, 0, 0)
#define MFMA(a, b, c) __builtin_amdgcn_mfma_f32_16x16x32_bf16((a), (b), (c), 0, 0, 0)
#define FENCE() asm volatile("" ::: "memory")
#define BAR()   do { FENCE(); __builtin_amdgcn_s_barrier(); FENCE(); } while (0)
#define WAITV(n) asm volatile("s_waitcnt vmcnt(" #n ")" ::: "memory")

// frag read from a 128-row x 128B LDS region; 3-bit XOR swizzle (conflict-free)
#define RDF(base, rp, ks) \
  (*(const bf16x8*)((base) + (rp) * 128 + ((((ks) * 64) + q16) ^ (((rp) & 7) << 4))))

// ---------------------------------------------------------------------------
// f32 -> bf16 conversion (memory-bound, 8 elems/thread)
// ---------------------------------------------------------------------------
__global__ __launch_bounds__(256) void cvt_kernel(
    const float* __restrict__ src, __bf16* __restrict__ dst)
{
  const size_t i = ((size_t)blockIdx.x * 256 + threadIdx.x) * 8;
  float4 a = *reinterpret_cast<const float4*>(src + i);
  float4 b = *reinterpret_cast<const float4*>(src + i + 4);
  bf16x8 r;
  r[0] = (__bf16)a.x; r[1] = (__bf16)a.y; r[2] = (__bf16)a.z; r[3] = (__bf16)a.w;
  r[4] = (__bf16)b.x; r[5] = (__bf16)b.y; r[6] = (__bf16)b.z; r[7] = (__bf16)b.w;
  *reinterpret_cast<bf16x8*>(dst + i) = r;
}

// ===========================================================================
// Pipelined fused gate+up GEMM.  BM=256 x BN=128, BK=64. 8 waves (4M x 2N).
// LDS/buffer (64KB): Ah0@0, Ah1@16K, G@32K, U@48K (each 128 rows x 128B).
// PIPELINE: phase p's MFMA consumes frags read in an EARLIER phase; phase p's
// ds_reads fetch for a later phase, overlapping MFMA (separate pipes).
//   ph0: MFMA aF0*wG   | read aF1        | stage so.Ah1[kt+1]
//   ph1: MFMA aF1*wG   | read wU (after) | stage so.U[kt+1]
//   ph2: MFMA aF0*wU   | read aF0'(after)| stage sb.Ah0[kt+2]
//   ph3: MFMA aF1*wU   | read wG'        | stage sb.G[kt+2]
// Each phase reads the region staged at the SAME phase of the previous tile
// (4 barriers back). WAITV(6)+BAR at phase start: every wave's drain of the
// read-target precedes the barrier, so all staging is proven landed.
// ===========================================================================
__global__ __launch_bounds__(512, 2) void gateup8_kernel(
    const __bf16* __restrict__ X, const __bf16* __restrict__ Gw,
    const __bf16* __restrict__ Uw, __bf16* __restrict__ act)
{
  extern __shared__ char smem[];   // 2 x 64KB
  const int tid  = threadIdx.x;
  const int lane = tid & 63;
  const int wave = tid >> 6;
  const int wm = wave >> 1, wn = wave & 1;
  const int e  = blockIdx.z;
  const int m0 = e * CHUNK + blockIdx.y * 256;   // row into X/act
  const int n0 = e * IDIM  + blockIdx.x * 128;   // row into Gw/Uw

  int su[2], skk[2];
#pragma unroll
  for (int j = 0; j < 2; ++j) {
    int P = j * 8192 + tid * 16;
    int L = P ^ (((P >> 7) & 7) << 4);   // same 3-bit involution as RDF
    su[j]  = L >> 7;
    skk[j] = (L & 127) >> 1;
  }
  const int ldsw = wave * 1024;

  auto stageA = [&](char* bb, int h, int kt2) {
#pragma unroll
    for (int j = 0; j < 2; ++j) {
      int u = su[j];
      int r = (u & 31) + h * 32 + (u >> 5) * 64;
      const __bf16* src = X + (size_t)(m0 + r) * HDIM + kt2 * 64 + skk[j];
      GLDS16(src, bb + h * 16384 + j * 8192 + ldsw);
    }
  };
  auto stageW = [&](char* bb, int w, int kt2) {   // w: 0=G, 1=U
    const __bf16* W = w ? Uw : Gw;
#pragma unroll
    for (int j = 0; j < 2; ++j) {
      const __bf16* src = W + (size_t)(n0 + su[j]) * HDIM + kt2 * 64 + skk[j];
      GLDS16(src, bb + 32768 + w * 16384 + j * 8192 + ldsw);
    }
  };

  f32x4 accg[4][4], accu[4][4];
#pragma unroll
  for (int m = 0; m < 4; ++m)
#pragma unroll
    for (int n = 0; n < 4; ++n)
#pragma unroll
      for (int j = 0; j < 4; ++j) { accg[m][n][j] = 0.f; accu[m][n][j] = 0.f; }

  const int frow = lane & 15;
  const int q16  = (lane >> 4) * 16;
  const int NT   = HDIM / 64;   // 32

  bf16x8 aF0[2][2], aF1[2][2], wG[4][2], wU[4][2];

  // ---- prologue: land Ah0[0],G[0]; read aF0,wG; queue 4 units ----
  {
    char* s0 = smem;
    char* s1 = smem + 65536;
    stageA(s0, 0, 0); stageW(s0, 0, 0);
    WAITV(0);
    BAR();
#pragma unroll
    for (int m = 0; m < 2; ++m) { int rp = wm * 32 + m * 16 + frow;
      aF0[m][0] = RDF(s0, rp, 0); aF0[m][1] = RDF(s0, rp, 1); }
#pragma unroll
    for (int n = 0; n < 4; ++n) { int rp = wn * 64 + n * 16 + frow;
      wG[n][0] = RDF(s0 + 32768, rp, 0); wG[n][1] = RDF(s0 + 32768, rp, 1); }
    stageA(s0, 1, 0);   // Ah1[0]
    stageW(s0, 1, 0);   // U[0]
    stageA(s1, 0, 1);   // Ah0[1]
    stageW(s1, 0, 1);   // G[1]
  }

  for (int kt = 0; kt < NT; ++kt) {
    char* sb = smem + (kt & 1) * 65536;
    char* so = smem + ((kt & 1) ^ 1) * 65536;

    // ---------------- phase 0: MFMA aF0*wG -> accg[0:2] ----------------
    if (kt + 1 < NT) { WAITV(6); } else { WAITV(2); }
    BAR();
    if (kt + 1 < NT) stageA(so, 1, kt + 1);
#pragma unroll
    for (int m = 0; m < 2; ++m) { int rp = wm * 32 + m * 16 + frow;
      aF1[m][0] = RDF(sb + 16384, rp, 0); aF1[m][1] = RDF(sb + 16384, rp, 1); }
    __builtin_amdgcn_s_setprio(1);
#pragma unroll
    for (int n = 0; n < 4; ++n)
#pragma unroll
      for (int m = 0; m < 2; ++m) {
        accg[m][n] = MFMA(aF0[m][0], wG[n][0], accg[m][n]);
        accg[m][n] = MFMA(aF0[m][1], wG[n][1], accg[m][n]);
      }
    __builtin_amdgcn_s_setprio(0);

    // ---------------- phase 1: MFMA aF1*wG -> accg[2:4] ----------------
    if (kt + 1 < NT) { WAITV(6); } else { WAITV(0); }
    BAR();
    if (kt + 1 < NT) stageW(so, 1, kt + 1);
    __builtin_amdgcn_s_setprio(1);
#pragma unroll
    for (int n = 0; n < 4; ++n)
#pragma unroll
      for (int m = 0; m < 2; ++m) {
        accg[2 + m][n] = MFMA(aF1[m][0], wG[n][0], accg[2 + m][n]);
        accg[2 + m][n] = MFMA(aF1[m][1], wG[n][1], accg[2 + m][n]);
      }
    __builtin_amdgcn_s_setprio(0);
#pragma unroll
    for (int n = 0; n < 4; ++n) { int rp = wn * 64 + n * 16 + frow;
      wU[n][0] = RDF(sb + 49152, rp, 0); wU[n][1] = RDF(sb + 49152, rp, 1); }

    // ---------------- phase 2: MFMA aF0*wU -> accu[0:2] ----------------
    if (kt + 1 < NT) { WAITV(6); }
    BAR();
    if (kt + 2 < NT) stageA(sb, 0, kt + 2);
    __builtin_amdgcn_s_setprio(1);
#pragma unroll
    for (int n = 0; n < 4; ++n)
#pragma unroll
      for (int m = 0; m < 2; ++m) {
        accu[m][n] = MFMA(aF0[m][0], wU[n][0], accu[m][n]);
        accu[m][n] = MFMA(aF0[m][1], wU[n][1], accu[m][n]);
      }
    __builtin_amdgcn_s_setprio(0);
    if (kt + 1 < NT) {
#pragma unroll
      for (int m = 0; m < 2; ++m) { int rp = wm * 32 + m * 16 + frow;
        aF0[m][0] = RDF(so, rp, 0); aF0[m][1] = RDF(so, rp, 1); }
    }

    // ---------------- phase 3: MFMA aF1*wU -> accu[2:4] ----------------
    if (kt + 2 < NT) { WAITV(6); } else if (kt + 1 < NT) { WAITV(4); }
    BAR();
    if (kt + 2 < NT) stageW(sb, 0, kt + 2);
    if (kt + 1 < NT) {
#pragma unroll
      for (int n = 0; n < 4; ++n) { int rp = wn * 64 + n * 16 + frow;
        wG[n][0] = RDF(so + 32768, rp, 0); wG[n][1] = RDF(so + 32768, rp, 1); }
    }
    __builtin_amdgcn_s_setprio(1);
#pragma unroll
    for (int n = 0; n < 4; ++n)
#pragma unroll
      for (int m = 0; m < 2; ++m) {
        accu[2 + m][n] = MFMA(aF1[m][0], wU[n][0], accu[2 + m][n]);
        accu[2 + m][n] = MFMA(aF1[m][1], wU[n][1], accu[2 + m][n]);
      }
    __builtin_amdgcn_s_setprio(0);
  }

  // epilogue: silu(g)*u -> bf16 act
  const int orow0 = m0 + wm * 64 + (lane >> 4) * 4;
  const int ocol0 = blockIdx.x * 128 + wn * 64 + frow;
#pragma unroll
  for (int m = 0; m < 4; ++m)
#pragma unroll
    for (int n = 0; n < 4; ++n)
#pragma unroll
      for (int j = 0; j < 4; ++j) {
        float g = accg[m][n][j];
        float u = accu[m][n][j];
        float s = g / (1.0f + __expf(-g));
        act[(size_t)(orow0 + m * 16 + j) * IDIM + (ocol0 + n * 16)] = (__bf16)(s * u);
      }
}

// ===========================================================================
// Pipelined down GEMM: out = act . Dw^T (f32). BM=256 x BN=256, BK=64.
// Identical skeleton to gateup8: 8 waves (4M x 2N), per-wave 64 x 128.
// B (Dw) split into two 128-col halves playing the G/U roles.
// LDS/buffer: Ah0@0, Ah1@16K, B0@32K, B1@48K.
//   ph0: MFMA aF0*bN0 -> accn0[0:2] | read aF1         | stage so.Ah1'
//   ph1: MFMA aF1*bN0 -> accn0[2:4] | read bN1 (after) | stage so.B1'
//   ph2: MFMA aF0*bN1 -> accn1[0:2] | read aF0' (after)| stage sb.Ah0''
//   ph3: MFMA aF1*bN1 -> accn1[2:4] | read bN0'        | stage sb.B0''
// ===========================================================================
__global__ __launch_bounds__(512, 2) void down8_kernel(
    const __bf16* __restrict__ act, const __bf16* __restrict__ Dw,
    float* __restrict__ out)
{
  extern __shared__ char smem[];
  const int tid  = threadIdx.x;
  const int lane = tid & 63;
  const int wave = tid >> 6;
  const int wm = wave >> 1, wc = wave & 1;
  const int e  = blockIdx.z;
  const int m0 = e * CHUNK + blockIdx.y * 256;   // row into act/out
  const int n0 = e * HDIM  + blockIdx.x * 256;   // row into Dw

  int su[2], skk[2];
#pragma unroll
  for (int j = 0; j < 2; ++j) {
    int P = j * 8192 + tid * 16;
    int L = P ^ (((P >> 7) & 7) << 4);
    su[j]  = L >> 7;
    skk[j] = (L & 127) >> 1;
  }
  const int ldsw = wave * 1024;

  auto stageA = [&](char* bb, int h, int kt2) {
#pragma unroll
    for (int j = 0; j < 2; ++j) {
      int u = su[j];
      int r = (u & 31) + h * 32 + (u >> 5) * 64;
      const __bf16* src = act + (size_t)(m0 + r) * IDIM + kt2 * 64 + skk[j];
      GLDS16(src, bb + h * 16384 + j * 8192 + ldsw);
    }
  };
  auto stageB = [&](char* bb, int h, int kt2) {   // Dw half h: cols (u&63)+h*64+(u>>6)*128
#pragma unroll
    for (int j = 0; j < 2; ++j) {
      int u = su[j];
      int r = (u & 63) + h * 64 + (u >> 6) * 128;
      const __bf16* src = Dw + (size_t)(n0 + r) * IDIM + kt2 * 64 + skk[j];
      GLDS16(src, bb + 32768 + h * 16384 + j * 8192 + ldsw);
    }
  };

  f32x4 accn0[4][4], accn1[4][4];
#pragma unroll
  for (int m = 0; m < 4; ++m)
#pragma unroll
    for (int n = 0; n < 4; ++n)
#pragma unroll
      for (int j = 0; j < 4; ++j) { accn0[m][n][j] = 0.f; accn1[m][n][j] = 0.f; }

  const int frow = lane & 15;
  const int q16  = (lane >> 4) * 16;
  const int NT   = IDIM / 64;   // 128

  bf16x8 aF0[2][2], aF1[2][2], bN0[4][2], bN1[4][2];

  {
    char* s0 = smem;
    char* s1 = smem + 65536;
    stageA(s0, 0, 0); stageB(s0, 0, 0);
    WAITV(0);
    BAR();
#pragma unroll
    for (int m = 0; m < 2; ++m) { int rp = wm * 32 + m * 16 + frow;
      aF0[m][0] = RDF(s0, rp, 0); aF0[m][1] = RDF(s0, rp, 1); }
#pragma unroll
    for (int n = 0; n < 4; ++n) { int rp = wc * 64 + n * 16 + frow;
      bN0[n][0] = RDF(s0 + 32768, rp, 0); bN0[n][1] = RDF(s0 + 32768, rp, 1); }
    stageA(s0, 1, 0);   // Ah1[0]
    stageB(s0, 1, 0);   // B1[0]
    stageA(s1, 0, 1);   // Ah0[1]
    stageB(s1, 0, 1);   // B0[1]
  }

  for (int kt = 0; kt < NT; ++kt) {
    char* sb = smem + (kt & 1) * 65536;
    char* so = smem + ((kt & 1) ^ 1) * 65536;

    // ---------------- phase 0 ----------------
    if (kt + 1 < NT) { WAITV(6); } else { WAITV(2); }
    BAR();
    if (kt + 1 < NT) stageA(so, 1, kt + 1);
#pragma unroll
    for (int m = 0; m < 2; ++m) { int rp = wm * 32 + m * 16 + frow;
      aF1[m][0] = RDF(sb + 16384, rp, 0); aF1[m][1] = RDF(sb + 16384, rp, 1); }
    __builtin_amdgcn_s_setprio(1);
#pragma unroll
    for (int n = 0; n < 4; ++n)
#pragma unroll
      for (int m = 0; m < 2; ++m) {
        accn0[m][n] = MFMA(aF0[m][0], bN0[n][0], accn0[m][n]);
        accn0[m][n] = MFMA(aF0[m][1], bN0[n][1], accn0[m][n]);
      }
    __builtin_amdgcn_s_setprio(0);

    // ---------------- phase 1 ----------------
    if (kt + 1 < NT) { WAITV(6); } else { WAITV(0); }
    BAR();
    if (kt + 1 < NT) stageB(so, 1, kt + 1);
    __builtin_amdgcn_s_setprio(1);
#pragma unroll
    for (int n = 0; n < 4; ++n)
#pragma unroll
      for (int m = 0; m < 2; ++m) {
        accn0[2 + m][n] = MFMA(aF1[m][0], bN0[n][0], accn0[2 + m][n]);
        accn0[2 + m][n] = MFMA(aF1[m][1], bN0[n][1], accn0[2 + m][n]);
      }
    __builtin_amdgcn_s_setprio(0);
#pragma unroll
    for (int n = 0; n < 4; ++n) { int rp = wc * 64 + n * 16 + frow;
      bN1[n][0] = RDF(sb + 49152, rp, 0); bN1[n][1] = RDF(sb + 49152, rp, 1); }

    // ---------------- phase 2 ----------------
    if (kt + 1 < NT) { WAITV(6); }
    BAR();
    if (kt + 2 < NT) stageA(sb, 0, kt + 2);
    __builtin_amdgcn_s_setprio(1);
#pragma unroll
    for (int n = 0; n < 4; ++n)
#pragma unroll
      for (int m = 0; m < 2; ++m) {
        accn1[m][n] = MFMA(aF0[m][0], bN1[n][0], accn1[m][n]);
        accn1[m][n] = MFMA(aF0[m][1], bN1[n][1], accn1[m][n]);
      }
    __builtin_amdgcn_s_setprio(0);
    if (kt + 1 < NT) {
#pragma unroll
      for (int m = 0; m < 2; ++m) { int rp = wm * 32 + m * 16 + frow;
        aF0[m][0] = RDF(so, rp, 0); aF0[m][1] = RDF(so, rp, 1); }
    }

    // ---------------- phase 3 ----------------
    if (kt + 2 < NT) { WAITV(6); } else if (kt + 1 < NT) { WAITV(4); }
    BAR();
    if (kt + 2 < NT) stageB(sb, 0, kt + 2);
    if (kt + 1 < NT) {
#pragma unroll
      for (int n = 0; n < 4; ++n) { int rp = wc * 64 + n * 16 + frow;
        bN0[n][0] = RDF(so + 32768, rp, 0); bN0[n][1] = RDF(so + 32768, rp, 1); }
    }
    __builtin_amdgcn_s_setprio(1);
#pragma unroll
    for (int n = 0; n < 4; ++n)
#pragma unroll
      for (int m = 0; m < 2; ++m) {
        accn1[2 + m][n] = MFMA(aF1[m][0], bN1[n][0], accn1[2 + m][n]);
        accn1[2 + m][n] = MFMA(aF1[m][1], bN1[n][1], accn1[2 + m][n]);
      }
    __builtin_amdgcn_s_setprio(0);
  }

  const int orow0 = m0 + wm * 64 + (lane >> 4) * 4;
  const int ocol0 = blockIdx.x * 256 + wc * 128 + frow;
#pragma unroll
  for (int m = 0; m < 4; ++m)
#pragma unroll
    for (int n = 0; n < 4; ++n)
#pragma unroll
      for (int j = 0; j < 4; ++j) {
        out[(size_t)(orow0 + m * 16 + j) * HDIM + (ocol0 + n * 16)] = accn0[m][n][j];
        out[(size_t)(orow0 + m * 16 + j) * HDIM + (ocol0 + 64 + n * 16)] = accn1[m][n][j];
      }
}

// ===========================================================================
// Fallback: round-3 kernels (128^2 2-barrier, per-expert) if ws is small.
// ===========================================================================
__global__ __launch_bounds__(256) void gateup2_kernel(
    const __bf16* __restrict__ X, const __bf16* __restrict__ Gw,
    const __bf16* __restrict__ Uw, __bf16* __restrict__ act)
{
  __shared__ __bf16 lds[2][3][128 * 32];
  const int tid  = threadIdx.x;
  const int lane = tid & 63;
  const int wave = tid >> 6;
  const int wr = wave >> 1, wc = wave & 1;
  const int m0 = blockIdx.x * 128;
  const int n0 = blockIdx.y * 128;

  int srow[2], scol[2];
#pragma unroll
  for (int h = 0; h < 2; ++h) {
    const int B  = h * 4096 + tid * 16;
    const int Bs = B ^ (((B >> 7) & 3) << 4);
    srow[h] = Bs >> 6;
    scol[h] = (Bs & 63) >> 1;
  }
  const int ldst_off[2] = { wave * 1024, 4096 + wave * 1024 };

  f32x4 accg[4][4], accu[4][4];
#pragma unroll
  for (int m = 0; m < 4; ++m)
#pragma unroll
    for (int n = 0; n < 4; ++n)
#pragma unroll
      for (int j = 0; j < 4; ++j) { accg[m][n][j] = 0.f; accu[m][n][j] = 0.f; }

  const int frow  = lane & 15;
  const int rdoff = ((lane >> 4) * 16) ^ (((frow >> 1) & 3) << 4);

  auto stage = [&](int buf, int kt) {
    const int k0 = kt * 32;
#pragma unroll
    for (int h = 0; h < 2; ++h) {
      GLDS16(X  + (size_t)(m0 + srow[h]) * HDIM + k0 + scol[h], (char*)&lds[buf][0][0] + ldst_off[h]);
      GLDS16(Gw + (size_t)(n0 + srow[h]) * HDIM + k0 + scol[h], (char*)&lds[buf][1][0] + ldst_off[h]);
      GLDS16(Uw + (size_t)(n0 + srow[h]) * HDIM + k0 + scol[h], (char*)&lds[buf][2][0] + ldst_off[h]);
    }
  };

  const int NT = HDIM / 32;
  stage(0, 0);
  int cur = 0;
  for (int kt = 0; kt < NT; ++kt) {
    __syncthreads();
    if (kt + 1 < NT) stage(cur ^ 1, kt + 1);
    const char* bA = (const char*)&lds[cur][0][0];
    const char* bG = (const char*)&lds[cur][1][0];
    const char* bU = (const char*)&lds[cur][2][0];
    bf16x8 af[4];
#pragma unroll
    for (int m = 0; m < 4; ++m)
      af[m] = *(const bf16x8*)(bA + (wr * 64 + m * 16 + frow) * 64 + rdoff);
#pragma unroll
    for (int n = 0; n < 4; ++n) {
      bf16x8 bg = *(const bf16x8*)(bG + (wc * 64 + n * 16 + frow) * 64 + rdoff);
      bf16x8 bu = *(const bf16x8*)(bU + (wc * 64 + n * 16 + frow) * 64 + rdoff);
#pragma unroll
      for (int m = 0; m < 4; ++m) {
        accg[m][n] = MFMA(af[m], bg, accg[m][n]);
        accu[m][n] = MFMA(af[m], bu, accu[m][n]);
      }
    }
    cur ^= 1;
  }
  const int orow = m0 + wr * 64 + (lane >> 4) * 4;
  const int ocol = n0 + wc * 64 + (lane & 15);
#pragma unroll
  for (int m = 0; m < 4; ++m)
#pragma unroll
    for (int n = 0; n < 4; ++n)
#pragma unroll
      for (int j = 0; j < 4; ++j) {
        float g = accg[m][n][j];
        float u = accu[m][n][j];
        float s = g / (1.0f + __expf(-g));
        act[(size_t)(orow + m * 16 + j) * IDIM + (ocol + n * 16)] = (__bf16)(s * u);
      }
}

__global__ __launch_bounds__(256) void down2_kernel(
    const __bf16* __restrict__ act, const __bf16* __restrict__ Dw,
    float* __restrict__ out)
{
  __shared__ __bf16 lds[2][2][128 * 32];
  const int tid  = threadIdx.x;
  const int lane = tid & 63;
  const int wave = tid >> 6;
  const int wr = wave >> 1, wc = wave & 1;
  const int m0 = blockIdx.x * 128;
  const int n0 = blockIdx.y * 128;

  int srow[2], scol[2];
#pragma unroll
  for (int h = 0; h < 2; ++h) {
    const int B  = h * 4096 + tid * 16;
    const int Bs = B ^ (((B >> 7) & 3) << 4);
    srow[h] = Bs >> 6;
    scol[h] = (Bs & 63) >> 1;
  }
  const int ldst_off[2] = { wave * 1024, 4096 + wave * 1024 };

  f32x4 acc[4][4];
#pragma unroll
  for (int m = 0; m < 4; ++m)
#pragma unroll
    for (int n = 0; n < 4; ++n)
#pragma unroll
      for (int j = 0; j < 4; ++j) acc[m][n][j] = 0.f;

  const int frow  = lane & 15;
  const int rdoff = ((lane >> 4) * 16) ^ (((frow >> 1) & 3) << 4);

  auto stage = [&](int buf, int kt) {
    const int k0 = kt * 32;
#pragma unroll
    for (int h = 0; h < 2; ++h) {
      GLDS16(act + (size_t)(m0 + srow[h]) * IDIM + k0 + scol[h], (char*)&lds[buf][0][0] + ldst_off[h]);
      GLDS16(Dw  + (size_t)(n0 + srow[h]) * IDIM + k0 + scol[h], (char*)&lds[buf][1][0] + ldst_off[h]);
    }
  };

  const int NT = IDIM / 32;
  stage(0, 0);
  int cur = 0;
  for (int kt = 0; kt < NT; ++kt) {
    __syncthreads();
    if (kt + 1 < NT) stage(cur ^ 1, kt + 1);
    const char* bA = (const char*)&lds[cur][0][0];
    const char* bW = (const char*)&lds[cur][1][0];
    bf16x8 af[4];
#pragma unroll
    for (int m = 0; m < 4; ++m)
      af[m] = *(const bf16x8*)(bA + (wr * 64 + m * 16 + frow) * 64 + rdoff);
#pragma unroll
    for (int n = 0; n < 4; ++n) {
      bf16x8 bw = *(const bf16x8*)(bW + (wc * 64 + n * 16 + frow) * 64 + rdoff);
#pragma unroll
      for (int m = 0; m < 4; ++m)
        acc[m][n] = MFMA(af[m], bw, acc[m][n]);
    }
    cur ^= 1;
  }
  const int orow = m0 + wr * 64 + (lane >> 4) * 4;
  const int ocol = n0 + wc * 64 + (lane & 15);
#pragma unroll
  for (int m = 0; m < 4; ++m)
#pragma unroll
    for (int n = 0; n < 4; ++n)
#pragma unroll
      for (int j = 0; j < 4; ++j)
        out[(size_t)(orow + m * 16 + j) * HDIM + (ocol + n * 16)] = acc[m][n][j];
}

// ---------------------------------------------------------------------------
extern "C" void kernel_launch(void* const* d_in, const int* in_sizes, int n_in,
                              void* d_out, int out_size, void* d_ws, size_t ws_size,
                              hipStream_t stream)
{
  const float* hidden = (const float*)d_in[0];
  const float* gate_w = (const float*)d_in[1];
  const float* up_w   = (const float*)d_in[2];
  const float* down_w = (const float*)d_in[3];
  float* out = (float*)d_out;

  const size_t SZ_X    = (size_t)32768 * HDIM;
  const size_t SZ_Wall = (size_t)E_NUM * IDIM * HDIM;
  const size_t SZ_ACT  = (size_t)32768 * IDIM;
  const size_t need8 = (SZ_X + 3 * SZ_Wall + SZ_ACT) * sizeof(__bf16);  // ~1.48 GB

  if (ws_size >= need8) {
    __bf16* xb  = (__bf16*)d_ws;
    __bf16* gwb = xb  + SZ_X;
    __bf16* uwb = gwb + SZ_Wall;
    __bf16* dwb = uwb + SZ_Wall;
    __bf16* actb = dwb + SZ_Wall;

    cvt_kernel<<<SZ_X    / 2048, 256, 0, stream>>>(hidden, xb);
    cvt_kernel<<<SZ_Wall / 2048, 256, 0, stream>>>(gate_w, gwb);
    cvt_kernel<<<SZ_Wall / 2048, 256, 0, stream>>>(up_w,   uwb);
    cvt_kernel<<<SZ_Wall / 2048, 256, 0, stream>>>(down_w, dwb);

    gateup8_kernel<<<dim3(IDIM / 128, CHUNK / 256, E_NUM), 512, 131072, stream>>>(xb, gwb, uwb, actb);
    down8_kernel  <<<dim3(HDIM / 256, CHUNK / 256, E_NUM), 512, 131072, stream>>>(actb, dwb, out);
  } else {
    const size_t sX = (size_t)CHUNK * HDIM;
    const size_t sW = (size_t)IDIM * HDIM;
    __bf16* xb = (__bf16*)d_ws;
    __bf16* gb = xb + sX;
    __bf16* ub = gb + sW;
    __bf16* db = ub + sW;
    __bf16* act = db + sW;
    for (int e = 0; e < E_NUM; ++e) {
      const float* Xe = hidden + (size_t)e * sX;
      const float* Ge = gate_w + (size_t)e * sW;
      const float* Ue = up_w   + (size_t)e * sW;
      const float* De = down_w + (size_t)e * sW;
      float* Oe = out + (size_t)e * CHUNK * HDIM;
      cvt_kernel<<<sX / 2048, 256, 0, stream>>>(Xe, xb);
      cvt_kernel<<<sW / 2048, 256, 0, stream>>>(Ge, gb);
      cvt_kernel<<<sW / 2048, 256, 0, stream>>>(Ue, ub);
      cvt_kernel<<<sW / 2048, 256, 0, stream>>>(De, db);
      gateup2_kernel<<<dim3(CHUNK / 128, IDIM / 128), 256, 0, stream>>>(xb, gb, ub, act);
      down2_kernel<<<dim3(CHUNK / 128, HDIM / 128), 256, 0, stream>>>(act, db, Oe);
    }
  }
}